// Round 6
// baseline (247.756 us; speedup 1.0000x reference)
//
#include <hip/hip_runtime.h>
#include <math.h>

// AttentionDecoder R13: 3 kernels, no polling, DROP-FREE tail.
// prep (1 blk wave-parallel MLP + zero scal) | score (proven pure GEMV) |
// tail (49 blocks x 1024): chunk in REGISTERS, local hist+scan -> local
//   top-50 bin superset -> per-block buf region with SLOT=4096 (= chunk size,
//   can NEVER drop); single done-counter; last block re-hists candidates
//   DIRECTLY FROM GLOBAL buf (no capped staging -- R12's absmax=18.6 bug was
//   CAP=4096 < C~4-6k dropping true top-50 entries), bin-compacts to C2
//   (~50-200, cap 2048 structurally safe), exact select, renorm, rewrite,
//   threefry-gumbel categorical.
// Superset proof: if s in block B sits below B's selected bin, >=50 elements
// of B are in strictly higher bins, all > s => s is at best global 51st.
// Fin bin proof: bins strictly above global-v50's bin hold <=49 candidates,
// so candidate-suffix first reaches 50 exactly at v50's bin.

#define SLOT 4096
#define MAXB 64
#define C2CAP 2048
#define NEG_INF (-__builtin_inff())

// order-preserving float->uint mapping (monotone increasing)
__device__ __forceinline__ unsigned int f2ord(float f){
  unsigned int b = __float_as_uint(f);
  return (b & 0x80000000u) ? ~b : (b | 0x80000000u);
}
__device__ __forceinline__ unsigned int rotl32(unsigned int x, int d){
  return (x << d) | (x >> (32 - d));
}

// JAX partitionable threefry, key (0,42): x0=idx>>32(=0), x1=idx; bits=w0^w1.
// gumbel = -log(-log(u)), u = bitcast((bits>>9)|0x3f800000)-1 clamped to tiny.
__device__ float gumbel_from_idx(unsigned int idx){
  unsigned int x0 = 0u, x1 = idx;
  const unsigned int ks0 = 0u, ks1 = 42u;
  const unsigned int ks2 = 0u ^ 42u ^ 0x1BD11BDAu;
  x0 += ks0; x1 += ks1;
#define TF_RND(r) { x0 += x1; x1 = rotl32(x1, (r)); x1 ^= x0; }
  TF_RND(13) TF_RND(15) TF_RND(26) TF_RND(6)
  x0 += ks1; x1 += ks2 + 1u;
  TF_RND(17) TF_RND(29) TF_RND(16) TF_RND(24)
  x0 += ks2; x1 += ks0 + 2u;
  TF_RND(13) TF_RND(15) TF_RND(26) TF_RND(6)
  x0 += ks0; x1 += ks1 + 3u;
  TF_RND(17) TF_RND(29) TF_RND(16) TF_RND(24)
  x0 += ks1; x1 += ks2 + 4u;
  TF_RND(13) TF_RND(15) TF_RND(26) TF_RND(6)
  x0 += ks2; x1 += ks0 + 5u;
#undef TF_RND
  unsigned int bits = x0 ^ x1;
  unsigned int fb = (bits >> 9) | 0x3f800000u;
  float f = __uint_as_float(fb) - 1.0f;
  float u = (f < 1.17549435e-38f) ? 1.17549435e-38f : f;
  return -logf(-logf(u));
}

// lh[2048] counts -> *u_lo_sh = lower edge of the bin where cumulative-from-
// top first reaches ktop (0 if never). Caller sets *csel_sh=-1 + sync before.
// All 1024 threads must call (uniform).
__device__ void hist_select(unsigned int* lh, unsigned int* suf, int* csel_sh,
                            unsigned int* u_lo_sh, int ktop, int t){
  if (t < 256){
    unsigned int csum = 0;
    #pragma unroll
    for (int k = 0; k < 8; ++k) csum += lh[t * 8 + k];
    suf[t] = csum;
  }
  __syncthreads();
  for (int d = 1; d < 256; d <<= 1){
    unsigned int add = 0u;
    if (t < 256 && t + d < 256) add = suf[t + d];
    __syncthreads();
    if (t < 256) suf[t] += add;
    __syncthreads();
  }
  if (t < 256){
    unsigned int st = suf[t];
    unsigned int sn = (t < 255) ? suf[t + 1] : 0u;
    if (st >= (unsigned)ktop && sn < (unsigned)ktop) *csel_sh = t;   // unique
  }
  __syncthreads();
  if (t == 0){
    int b_sel = 0;
    int c = *csel_sh;
    if (c >= 0){
      unsigned int cum = (c < 255) ? suf[c + 1] : 0u;
      for (int bi = 8 * c + 7; bi >= 8 * c; --bi){
        cum += lh[bi];
        if (cum >= (unsigned)ktop){ b_sel = bi; break; }
      }
    }
    *u_lo_sh = ((unsigned int)b_sel) << 21;
  }
  __syncthreads();
}

// Wave-parallel MLP: q = Wq @ [cur;ctx] (half-wave per row, coalesced float4,
// 5-shfl reduce), then v = Wk^T q (split-K across 2 thread-halves).
// Also zeroes scal (done-counter) for k_tail.
__global__ __launch_bounds__(256) void k_prep(const float* __restrict__ cur,
    const float* __restrict__ ctx, const float* __restrict__ Wq,
    const float* __restrict__ Wk, float* __restrict__ v,
    unsigned int* __restrict__ scal_u){
  __shared__ float q[128];
  __shared__ float vpart[256];
  int t = threadIdx.x;
  int lane = t & 63, wave = t >> 6;
  int hl = lane & 31, hi = lane >> 5;
  if (t < 16) scal_u[t] = 0u;
  float4 cb0 = ((const float4*)cur)[hl];
  float4 cb1 = ((const float4*)ctx)[hl];
  const float4* Wq4 = (const float4*)Wq;
  #pragma unroll 4
  for (int i = 0; i < 16; ++i){
    int row = wave * 32 + 2 * i + hi;          // 4 waves x 16 iters x 2 rows = 128
    float4 w0 = Wq4[row * 64 + hl];            // coalesced 512B per half-wave
    float4 w1 = Wq4[row * 64 + 32 + hl];
    float d = fmaf(w0.x, cb0.x, fmaf(w0.y, cb0.y, fmaf(w0.z, cb0.z, w0.w * cb0.w)));
    d = fmaf(w1.x, cb1.x, fmaf(w1.y, cb1.y, fmaf(w1.z, cb1.z, fmaf(w1.w, cb1.w, d))));
    d += __shfl_xor(d, 1, 64);
    d += __shfl_xor(d, 2, 64);
    d += __shfl_xor(d, 4, 64);
    d += __shfl_xor(d, 8, 64);
    d += __shfl_xor(d, 16, 64);
    if (hl == 0) q[row] = d;
  }
  __syncthreads();
  // v[col] = sum_h q[h]*Wk[h*128+col]; split h-range across two 128-thread halves
  int col = t & 127, half = t >> 7;
  const float* wkp = Wk + half * 64 * 128 + col;
  const float* qp  = q + half * 64;
  float acc = 0.f;
  #pragma unroll 8
  for (int h = 0; h < 64; ++h) acc = fmaf(qp[h], wkp[h * 128], acc);
  vpart[t] = acc;
  __syncthreads();
  if (t < 128) v[t] = vpart[t] + vpart[t + 128];
}

// PURE GEMV (proven). Half-wave per row (32 lanes x float4 = 512B row),
// 16 rows/wave, 64 rows/block. All 8 loads in flight before FMAs. No atomics.
__global__ __launch_bounds__(256) void k_score(const float* __restrict__ cand,
    const int* __restrict__ mask, const float* __restrict__ v,
    float* __restrict__ scores, float* __restrict__ out, int N){
  const float NLOG = logf(1e-10f);
  int t = threadIdx.x;
  int lane = t & 63, wave = t >> 6;
  int hi = lane >> 5, hl = lane & 31;
  float4 v4 = ((const float4*)v)[hl];
  const float4* cp = (const float4*)cand;
  int base = (blockIdx.x * 4 + wave) * 16;
  float4 c[8];
  #pragma unroll
  for (int k = 0; k < 8; ++k){                 // phase 1: 8 loads in flight
    int r = base + 2 * k + hi;
    r = (r < N) ? r : (N - 1);                 // clamp: load stays unconditional
    c[k] = cp[(size_t)r * 32 + hl];
  }
  float p[8];
  #pragma unroll
  for (int k = 0; k < 8; ++k)                  // phase 2: consume
    p[k] = fmaf(c[k].x, v4.x, fmaf(c[k].y, v4.y, fmaf(c[k].z, v4.z, c[k].w * v4.w)));
  #pragma unroll
  for (int k = 0; k < 8; ++k){                 // 8 independent 5-shfl chains
    p[k] += __shfl_xor(p[k], 1, 64);
    p[k] += __shfl_xor(p[k], 2, 64);
    p[k] += __shfl_xor(p[k], 4, 64);
    p[k] += __shfl_xor(p[k], 8, 64);
    p[k] += __shfl_xor(p[k], 16, 64);
  }
  float sv = p[0];
  #pragma unroll
  for (int k = 1; k < 8; ++k) sv = (hl == k) ? p[k] : sv;
  if (hl < 8){                                 // writer lanes
    int r = base + 2 * hl + hi;
    if (r < N) scores[r] = mask[r] ? sv : NEG_INF;
  }
  if (t < 16){                                 // default output value, float4
    int o4 = blockIdx.x * 16 + t;
    if (o4 * 4 + 3 < N){
      ((float4*)out)[o4] = make_float4(NLOG, NLOG, NLOG, NLOG);
    } else {
      #pragma unroll
      for (int e = 0; e < 4; ++e){ int i = o4 * 4 + e; if (i < N) out[i] = NLOG; }
    }
  }
}

// Single tail launch, nb (<=49) blocks x 1024 thr, no polling, drop-free.
__global__ __launch_bounds__(1024) void k_tail(const float* __restrict__ scores,
    unsigned int* __restrict__ scal_u, float* __restrict__ zpart,
    unsigned int* __restrict__ cnt, unsigned int* __restrict__ buf_idx,
    float* __restrict__ buf_s, float* __restrict__ out,
    int N, int ktop, int nb){
  __shared__ unsigned int lh[2048];
  __shared__ unsigned int suf[256];
  __shared__ float s2[C2CAP];
  __shared__ unsigned int i2[C2CAP];
  __shared__ unsigned int cnt_l[MAXB], offs[MAXB];
  __shared__ float wred[16];
  __shared__ float rv[16], rl[16];
  __shared__ unsigned int ri[16];
  __shared__ float Z_sh, thr_sh, lnD_sh;
  __shared__ unsigned int u_lo_sh;
  __shared__ int csel_sh, pos_sh, last_sh;
  int t = threadIdx.x, b = blockIdx.x;
  int lane = t & 63, wave = t >> 6;
  for (int k = t; k < 2048; k += 1024) lh[k] = 0u;
  if (t == 0){ pos_sh = 0; csel_sh = -1; }
  __syncthreads();
  // ---- phase 1: chunk -> REGISTERS, local hist, Z partial ----
  int base = b * 4096;
  int i0 = base + 4 * t;
  float4 s4 = make_float4(NEG_INF, NEG_INF, NEG_INF, NEG_INF);
  if (i0 + 3 < N) s4 = ((const float4*)scores)[(base >> 2) + t];
  else {
    if (i0     < N) s4.x = scores[i0];
    if (i0 + 1 < N) s4.y = scores[i0 + 1];
    if (i0 + 2 < N) s4.z = scores[i0 + 2];
  }
  float ez = 0.f;
#define HVISIT(s_) { float sx = (s_); if (sx > NEG_INF){ \
    atomicAdd(&lh[f2ord(sx) >> 21], 1u); ez += expf(sx); } }
  HVISIT(s4.x) HVISIT(s4.y) HVISIT(s4.z) HVISIT(s4.w)
#undef HVISIT
  #pragma unroll
  for (int off = 32; off; off >>= 1) ez += __shfl_xor(ez, off, 64);
  if (lane == 0) wred[wave] = ez;
  __syncthreads();                             // lh + wred complete
  // ---- phase 2: LOCAL suffix scan -> local top-ktop bin edge ----
  hist_select(lh, suf, &csel_sh, &u_lo_sh, ktop, t);
  // ---- phase 3: gather local superset (SLOT = chunk size: never drops) ----
  unsigned int u_lo = u_lo_sh;
#define GVISIT(s_, i_) { float sx = (s_); \
    if (sx > NEG_INF && f2ord(sx) >= u_lo && (i_) < N){ \
      int p = atomicAdd(&pos_sh, 1); \
      buf_s[(size_t)b * SLOT + p] = sx; \
      buf_idx[(size_t)b * SLOT + p] = (unsigned int)(i_); } }
  GVISIT(s4.x, i0) GVISIT(s4.y, i0 + 1) GVISIT(s4.z, i0 + 2) GVISIT(s4.w, i0 + 3)
#undef GVISIT
  __syncthreads();                             // drains buf stores (vmcnt@barrier)
  if (t == 0){
    cnt[b] = (unsigned int)pos_sh;
    float z = 0.f;
    for (int w = 0; w < 16; ++w) z += wred[w];
    zpart[b] = z;
    __threadfence();
    unsigned int old = atomicAdd(&scal_u[8], 1u);   // single-shot, chain <= nb
    last_sh = (old == (unsigned)(nb - 1));
  }
  __syncthreads();
  if (!last_sh) return;
  __threadfence();
  // ---- fin (last block only) ----
  if (t < nb) cnt_l[t] = cnt[t];
  {
    float z = 0.f;
    if (t < 64){
      z = (t < nb) ? zpart[t] : 0.f;
      #pragma unroll
      for (int off = 32; off; off >>= 1) z += __shfl_xor(z, off, 64);
    }
    if (t == 0){ Z_sh = z; thr_sh = NEG_INF; pos_sh = 0; csel_sh = -1; }
  }
  for (int k = t; k < 2048; k += 1024) lh[k] = 0u;   // reset hist for round 2
  __syncthreads();
  // re-hist ALL candidates straight from global buf (uncapped; L2-resident)
  for (int b2 = 0; b2 < nb; ++b2){
    unsigned int cb = cnt_l[b2];
    for (unsigned int j = t; j < cb; j += 1024)
      atomicAdd(&lh[f2ord(buf_s[(size_t)b2 * SLOT + j]) >> 21], 1u);
  }
  __syncthreads();
  hist_select(lh, suf, &csel_sh, &u_lo_sh, ktop, t);
  // compact candidates >= global bin edge into LDS (C2 ~ 50-200)
  unsigned int u_lo2 = u_lo_sh;
  for (int b2 = 0; b2 < nb; ++b2){
    unsigned int cb = cnt_l[b2];
    for (unsigned int j = t; j < cb; j += 1024){
      float sx = buf_s[(size_t)b2 * SLOT + j];
      if (f2ord(sx) >= u_lo2){
        int p = atomicAdd(&pos_sh, 1);
        if (p < C2CAP){ s2[p] = sx; i2[p] = buf_idx[(size_t)b2 * SLOT + j]; }
      }
    }
  }
  __syncthreads();
  int C2 = (pos_sh > C2CAP) ? C2CAP : pos_sh;
  // ---- exact rank-select on C2 entries (broadcast LDS reads) ----
  if (C2 > ktop){
    for (int j = t; j < C2; j += 1024){
      float sj = s2[j];
      int g = 0, e = 0;
      for (int k2 = 0; k2 < C2; ++k2){
        float sk = s2[k2];
        g += (sk > sj);
        e += (sk == sj);
      }
      if (g < ktop && g + e >= ktop) thr_sh = sj;   // all writers same value
    }
  }
  __syncthreads();
  float s_thr = thr_sh;
  float part = 0.f;
  for (int j = t; j < C2; j += 1024){
    float sj = s2[j];
    if (sj >= s_thr) part += expf(sj);
  }
  #pragma unroll
  for (int off = 32; off; off >>= 1) part += __shfl_xor(part, off, 64);
  if (lane == 0) wred[wave] = part;
  __syncthreads();
  if (t == 0){
    float T = 0.f;
    for (int w = 0; w < 16; ++w) T += wred[w];
    lnD_sh = logf(T + 1e-10f * Z_sh);          // D = Z*(sum_top p + 1e-10)
  }
  __syncthreads();
  float lnD = lnD_sh;
  for (int j = t; j < C2; j += 1024){          // rewrite included entries
    float sj = s2[j];
    if (sj >= s_thr) out[i2[j]] = logf(expf(sj - lnD) + 1e-10f);
  }
  float bestv = NEG_INF, bestlogit = NEG_INF;  // gumbel categorical
  unsigned int bestidx = 0xFFFFFFFFu;
  for (int j = t; j < C2; j += 1024){
    float sj = s2[j];
    if (sj >= s_thr){
      unsigned int idx = i2[j];
      float logit = sj - lnD;                  // log(filtered)
      float val = logit + gumbel_from_idx(idx);
      if (val > bestv || (val == bestv && idx < bestidx)){
        bestv = val; bestlogit = logit; bestidx = idx;
      }
    }
  }
  #pragma unroll
  for (int off = 32; off; off >>= 1){
    float ov = __shfl_xor(bestv, off, 64);
    float ol = __shfl_xor(bestlogit, off, 64);
    unsigned int oi = (unsigned int)__shfl_xor((int)bestidx, off, 64);
    if (ov > bestv || (ov == bestv && oi < bestidx)){
      bestv = ov; bestlogit = ol; bestidx = oi;
    }
  }
  if (lane == 0){ rv[wave] = bestv; rl[wave] = bestlogit; ri[wave] = bestidx; }
  __syncthreads();
  if (t == 0){
    for (int w = 1; w < 16; ++w){
      if (rv[w] > rv[0] || (rv[w] == rv[0] && ri[w] < ri[0])){
        rv[0] = rv[w]; rl[0] = rl[w]; ri[0] = ri[w];
      }
    }
    out[N] = rl[0];                 // log_prob_action
    out[N + 1] = (float)ri[0];      // action_idx
  }
}

extern "C" void kernel_launch(void* const* d_in, const int* in_sizes, int n_in,
                              void* d_out, int out_size, void* d_ws, size_t ws_size,
                              hipStream_t stream){
  const float* cur  = (const float*)d_in[0];
  const float* ctx  = (const float*)d_in[1];
  const float* cand = (const float*)d_in[2];
  const float* Wq   = (const float*)d_in[3];
  const float* Wk   = (const float*)d_in[4];
  const int*   mask = (const int*)d_in[5];
  int N = in_sizes[5];
  float* out = (float*)d_out;

  char* ws = (char*)d_ws;
  unsigned int* scal_u  = (unsigned int*)ws;                  // 64B ([8]=done)
  float*        v       = (float*)(ws + 512);                 // 512B
  float*        zpart   = (float*)(ws + 1024);                // MAXB*4
  unsigned int* cnt     = (unsigned int*)(ws + 1536);         // MAXB*4
  float*        scores  = (float*)(ws + 4096);                // N*4, 16B-aligned
  char*         bufbase = ws + 4096 + (((size_t)N * 4 + 255) & ~255ull);
  float*        buf_s   = (float*)bufbase;                    // MAXB*SLOT*4 = 1MB
  unsigned int* buf_idx = (unsigned int*)(bufbase + (size_t)MAXB * SLOT * 4);

  int ktop = N / 2; if (ktop < 1) ktop = 1; if (ktop > 50) ktop = 50;
  int g_score = (N + 63) / 64;          // one 64-row tile per block
  int nb = (N + 4095) / 4096;           // 49 for N=200000
  if (nb > MAXB) nb = MAXB;             // (N fixed at 200000; guard only)

  k_prep<<<1, 256, 0, stream>>>(cur, ctx, Wq, Wk, v, scal_u);
  k_score<<<g_score, 256, 0, stream>>>(cand, mask, v, scores, out, N);
  k_tail<<<nb, 1024, 0, stream>>>(scores, scal_u, zpart, cnt,
                                  buf_idx, buf_s, out, N, ktop, nb);
}

// Round 7
// 206.183 us; speedup vs baseline: 1.2016x; 1.2016x over previous
//
#include <hip/hip_runtime.h>
#include <math.h>

// AttentionDecoder R14: 3 kernels, no polling, drop-free, NO serialized
// global loops in the single-block fin.
// prep (1 blk MLP + zero hist/scal) | score (proven pure GEMV) |
// tail (49 blk x 1024): chunk in regs, LDS hist + Z; local hist_select ->
//   local top-50 bin superset gather into per-block buf (SLOT=4096=chunk,
//   never drops); flush LDS hist -> GLOBAL hist (chains<=49); done-counter;
//   last block: coalesced hist load -> global v50 bin edge (R7 semantics),
//   prefix offs + per-thread binary-search indexed compact sweep over buf
//   (4 independent iterations -- pipelined, no per-iteration vmcnt chain),
//   exact rank-select, renorm, rewrite, threefry-gumbel categorical.
// R13 lesson: fin's 2x49-iteration rolled global loops serialized on
// cross-XCD remote-dirty reads (~0.9us each) = 85us. Single-block global
// reads must be independent+wide+pipelined, never latency-chained.

#define SLOT 4096
#define MAXB 64
#define C2CAP 2048
#define NEG_INF (-__builtin_inff())

// order-preserving float->uint mapping (monotone increasing)
__device__ __forceinline__ unsigned int f2ord(float f){
  unsigned int b = __float_as_uint(f);
  return (b & 0x80000000u) ? ~b : (b | 0x80000000u);
}
__device__ __forceinline__ unsigned int rotl32(unsigned int x, int d){
  return (x << d) | (x >> (32 - d));
}

// JAX partitionable threefry, key (0,42): x0=idx>>32(=0), x1=idx; bits=w0^w1.
// gumbel = -log(-log(u)), u = bitcast((bits>>9)|0x3f800000)-1 clamped to tiny.
__device__ float gumbel_from_idx(unsigned int idx){
  unsigned int x0 = 0u, x1 = idx;
  const unsigned int ks0 = 0u, ks1 = 42u;
  const unsigned int ks2 = 0u ^ 42u ^ 0x1BD11BDAu;
  x0 += ks0; x1 += ks1;
#define TF_RND(r) { x0 += x1; x1 = rotl32(x1, (r)); x1 ^= x0; }
  TF_RND(13) TF_RND(15) TF_RND(26) TF_RND(6)
  x0 += ks1; x1 += ks2 + 1u;
  TF_RND(17) TF_RND(29) TF_RND(16) TF_RND(24)
  x0 += ks2; x1 += ks0 + 2u;
  TF_RND(13) TF_RND(15) TF_RND(26) TF_RND(6)
  x0 += ks0; x1 += ks1 + 3u;
  TF_RND(17) TF_RND(29) TF_RND(16) TF_RND(24)
  x0 += ks1; x1 += ks2 + 4u;
  TF_RND(13) TF_RND(15) TF_RND(26) TF_RND(6)
  x0 += ks2; x1 += ks0 + 5u;
#undef TF_RND
  unsigned int bits = x0 ^ x1;
  unsigned int fb = (bits >> 9) | 0x3f800000u;
  float f = __uint_as_float(fb) - 1.0f;
  float u = (f < 1.17549435e-38f) ? 1.17549435e-38f : f;
  return -logf(-logf(u));
}

// lh[2048] counts -> *u_lo_sh = lower edge of the bin where cumulative-from-
// top first reaches ktop (0 if never). Caller sets *csel_sh=-1 + sync before.
// All 1024 threads must call (uniform). lh is not modified.
__device__ void hist_select(unsigned int* lh, unsigned int* suf, int* csel_sh,
                            unsigned int* u_lo_sh, int ktop, int t){
  if (t < 256){
    unsigned int csum = 0;
    #pragma unroll
    for (int k = 0; k < 8; ++k) csum += lh[t * 8 + k];
    suf[t] = csum;
  }
  __syncthreads();
  for (int d = 1; d < 256; d <<= 1){
    unsigned int add = 0u;
    if (t < 256 && t + d < 256) add = suf[t + d];
    __syncthreads();
    if (t < 256) suf[t] += add;
    __syncthreads();
  }
  if (t < 256){
    unsigned int st = suf[t];
    unsigned int sn = (t < 255) ? suf[t + 1] : 0u;
    if (st >= (unsigned)ktop && sn < (unsigned)ktop) *csel_sh = t;   // unique
  }
  __syncthreads();
  if (t == 0){
    int b_sel = 0;
    int c = *csel_sh;
    if (c >= 0){
      unsigned int cum = (c < 255) ? suf[c + 1] : 0u;
      for (int bi = 8 * c + 7; bi >= 8 * c; --bi){
        cum += lh[bi];
        if (cum >= (unsigned)ktop){ b_sel = bi; break; }
      }
    }
    *u_lo_sh = ((unsigned int)b_sel) << 21;
  }
  __syncthreads();
}

// Wave-parallel MLP: q = Wq @ [cur;ctx] (half-wave per row, coalesced float4,
// 5-shfl reduce), then v = Wk^T q (split-K across 2 thread-halves).
// Also zeroes global hist + scal for k_tail.
__global__ __launch_bounds__(256) void k_prep(const float* __restrict__ cur,
    const float* __restrict__ ctx, const float* __restrict__ Wq,
    const float* __restrict__ Wk, float* __restrict__ v,
    unsigned int* __restrict__ hist, unsigned int* __restrict__ scal_u){
  __shared__ float q[128];
  __shared__ float vpart[256];
  int t = threadIdx.x;
  int lane = t & 63, wave = t >> 6;
  int hl = lane & 31, hi = lane >> 5;
  for (int k = t; k < 2048; k += 256) hist[k] = 0u;
  if (t < 16) scal_u[t] = 0u;
  float4 cb0 = ((const float4*)cur)[hl];
  float4 cb1 = ((const float4*)ctx)[hl];
  const float4* Wq4 = (const float4*)Wq;
  #pragma unroll 4
  for (int i = 0; i < 16; ++i){
    int row = wave * 32 + 2 * i + hi;          // 4 waves x 16 iters x 2 rows = 128
    float4 w0 = Wq4[row * 64 + hl];            // coalesced 512B per half-wave
    float4 w1 = Wq4[row * 64 + 32 + hl];
    float d = fmaf(w0.x, cb0.x, fmaf(w0.y, cb0.y, fmaf(w0.z, cb0.z, w0.w * cb0.w)));
    d = fmaf(w1.x, cb1.x, fmaf(w1.y, cb1.y, fmaf(w1.z, cb1.z, fmaf(w1.w, cb1.w, d))));
    d += __shfl_xor(d, 1, 64);
    d += __shfl_xor(d, 2, 64);
    d += __shfl_xor(d, 4, 64);
    d += __shfl_xor(d, 8, 64);
    d += __shfl_xor(d, 16, 64);
    if (hl == 0) q[row] = d;
  }
  __syncthreads();
  // v[col] = sum_h q[h]*Wk[h*128+col]; split h-range across two 128-thread halves
  int col = t & 127, half = t >> 7;
  const float* wkp = Wk + half * 64 * 128 + col;
  const float* qp  = q + half * 64;
  float acc = 0.f;
  #pragma unroll 8
  for (int h = 0; h < 64; ++h) acc = fmaf(qp[h], wkp[h * 128], acc);
  vpart[t] = acc;
  __syncthreads();
  if (t < 128) v[t] = vpart[t] + vpart[t + 128];
}

// PURE GEMV (proven). Half-wave per row (32 lanes x float4 = 512B row),
// 16 rows/wave, 64 rows/block. All 8 loads in flight before FMAs. No atomics.
__global__ __launch_bounds__(256) void k_score(const float* __restrict__ cand,
    const int* __restrict__ mask, const float* __restrict__ v,
    float* __restrict__ scores, float* __restrict__ out, int N){
  const float NLOG = logf(1e-10f);
  int t = threadIdx.x;
  int lane = t & 63, wave = t >> 6;
  int hi = lane >> 5, hl = lane & 31;
  float4 v4 = ((const float4*)v)[hl];
  const float4* cp = (const float4*)cand;
  int base = (blockIdx.x * 4 + wave) * 16;
  float4 c[8];
  #pragma unroll
  for (int k = 0; k < 8; ++k){                 // phase 1: 8 loads in flight
    int r = base + 2 * k + hi;
    r = (r < N) ? r : (N - 1);                 // clamp: load stays unconditional
    c[k] = cp[(size_t)r * 32 + hl];
  }
  float p[8];
  #pragma unroll
  for (int k = 0; k < 8; ++k)                  // phase 2: consume
    p[k] = fmaf(c[k].x, v4.x, fmaf(c[k].y, v4.y, fmaf(c[k].z, v4.z, c[k].w * v4.w)));
  #pragma unroll
  for (int k = 0; k < 8; ++k){                 // 8 independent 5-shfl chains
    p[k] += __shfl_xor(p[k], 1, 64);
    p[k] += __shfl_xor(p[k], 2, 64);
    p[k] += __shfl_xor(p[k], 4, 64);
    p[k] += __shfl_xor(p[k], 8, 64);
    p[k] += __shfl_xor(p[k], 16, 64);
  }
  float sv = p[0];
  #pragma unroll
  for (int k = 1; k < 8; ++k) sv = (hl == k) ? p[k] : sv;
  if (hl < 8){                                 // writer lanes
    int r = base + 2 * hl + hi;
    if (r < N) scores[r] = mask[r] ? sv : NEG_INF;
  }
  if (t < 16){                                 // default output value, float4
    int o4 = blockIdx.x * 16 + t;
    if (o4 * 4 + 3 < N){
      ((float4*)out)[o4] = make_float4(NLOG, NLOG, NLOG, NLOG);
    } else {
      #pragma unroll
      for (int e = 0; e < 4; ++e){ int i = o4 * 4 + e; if (i < N) out[i] = NLOG; }
    }
  }
}

// Single tail launch, nb (<=49) blocks x 1024 thr, no polling, drop-free.
__global__ __launch_bounds__(1024) void k_tail(const float* __restrict__ scores,
    unsigned int* __restrict__ scal_u, unsigned int* __restrict__ hist,
    float* __restrict__ zpart, unsigned int* __restrict__ cnt,
    unsigned int* __restrict__ buf_idx, float* __restrict__ buf_s,
    float* __restrict__ out, int N, int ktop, int nb){
  __shared__ unsigned int lh[2048];
  __shared__ unsigned int suf[256];
  __shared__ float s2[C2CAP];
  __shared__ unsigned int i2[C2CAP];
  __shared__ unsigned int cnt_l[MAXB], offs[MAXB];
  __shared__ float wred[16];
  __shared__ float rv[16], rl[16];
  __shared__ unsigned int ri[16];
  __shared__ float Z_sh, thr_sh, lnD_sh;
  __shared__ unsigned int u_lo_sh;
  __shared__ int csel_sh, pos_sh, C_sh, last_sh;
  int t = threadIdx.x, b = blockIdx.x;
  int lane = t & 63, wave = t >> 6;
  for (int k = t; k < 2048; k += 1024) lh[k] = 0u;
  if (t == 0){ pos_sh = 0; csel_sh = -1; }
  __syncthreads();
  // ---- phase 1: chunk -> REGISTERS, local hist, Z partial ----
  int base = b * 4096;
  int i0 = base + 4 * t;
  float4 s4 = make_float4(NEG_INF, NEG_INF, NEG_INF, NEG_INF);
  if (i0 + 3 < N) s4 = ((const float4*)scores)[(base >> 2) + t];
  else {
    if (i0     < N) s4.x = scores[i0];
    if (i0 + 1 < N) s4.y = scores[i0 + 1];
    if (i0 + 2 < N) s4.z = scores[i0 + 2];
  }
  float ez = 0.f;
#define HVISIT(s_) { float sx = (s_); if (sx > NEG_INF){ \
    atomicAdd(&lh[f2ord(sx) >> 21], 1u); ez += expf(sx); } }
  HVISIT(s4.x) HVISIT(s4.y) HVISIT(s4.z) HVISIT(s4.w)
#undef HVISIT
  #pragma unroll
  for (int off = 32; off; off >>= 1) ez += __shfl_xor(ez, off, 64);
  if (lane == 0) wred[wave] = ez;
  __syncthreads();                             // lh + wred complete
  // ---- phase 2: LOCAL suffix scan -> local top-ktop bin edge ----
  hist_select(lh, suf, &csel_sh, &u_lo_sh, ktop, t);
  // ---- phase 3: gather local superset (SLOT = chunk size: never drops),
  //      and flush LDS hist -> global hist (chains <= nb) ----
  unsigned int u_lo = u_lo_sh;
#define GVISIT(s_, i_) { float sx = (s_); \
    if (sx > NEG_INF && f2ord(sx) >= u_lo && (i_) < N){ \
      int p = atomicAdd(&pos_sh, 1); \
      buf_s[(size_t)b * SLOT + p] = sx; \
      buf_idx[(size_t)b * SLOT + p] = (unsigned int)(i_); } }
  GVISIT(s4.x, i0) GVISIT(s4.y, i0 + 1) GVISIT(s4.z, i0 + 2) GVISIT(s4.w, i0 + 3)
#undef GVISIT
  for (int k = t; k < 2048; k += 1024){
    unsigned int cc = lh[k];
    if (cc) atomicAdd(&hist[k], cc);
  }
  __syncthreads();                             // drains buf stores + hist atomics
  if (t == 0){
    cnt[b] = (unsigned int)pos_sh;
    float z = 0.f;
    for (int w = 0; w < 16; ++w) z += wred[w];
    zpart[b] = z;
    __threadfence();
    unsigned int old = atomicAdd(&scal_u[8], 1u);   // single-shot, chain <= nb
    last_sh = (old == (unsigned)(nb - 1));
  }
  __syncthreads();
  if (!last_sh) return;
  __threadfence();
  // ---- fin (last block only): all global reads independent + pipelined ----
  if (t < nb) cnt_l[t] = cnt[t];
  for (int k = t; k < 2048; k += 1024) lh[k] = hist[k];   // coalesced, 2 iters
  {
    float z = 0.f;
    if (t < 64){
      z = (t < nb) ? zpart[t] : 0.f;
      #pragma unroll
      for (int off = 32; off; off >>= 1) z += __shfl_xor(z, off, 64);
    }
    if (t == 0){ Z_sh = z; thr_sh = NEG_INF; pos_sh = 0; csel_sh = -1; }
  }
  __syncthreads();
  if (t == 0){
    unsigned int acc = 0;
    for (int b2 = 0; b2 < nb; ++b2){ offs[b2] = acc; acc += cnt_l[b2]; }
    C_sh = (int)acc;
  }
  __syncthreads();
  // global v50 bin edge from the FULL global hist (R7 semantics)
  hist_select(lh, suf, &csel_sh, &u_lo_sh, ktop, t);
  unsigned int u_lo2 = u_lo_sh;
  int C = C_sh;
  // indexed compact sweep: p -> (block, j) via LDS binary search; all loads
  // independent across p-iterations (C ~ 3.2k -> ~4 strided iterations)
  for (int p = t; p < C; p += 1024){
    int lo = 0, hi2 = nb - 1;
    while (lo < hi2){
      int mid = (lo + hi2 + 1) >> 1;
      if (offs[mid] <= (unsigned)p) lo = mid; else hi2 = mid - 1;
    }
    unsigned int j = (unsigned)p - offs[lo];
    float sx = buf_s[(size_t)lo * SLOT + j];
    if (sx > NEG_INF && f2ord(sx) >= u_lo2){
      int q = atomicAdd(&pos_sh, 1);
      if (q < C2CAP){ s2[q] = sx; i2[q] = buf_idx[(size_t)lo * SLOT + j]; }
    }
  }
  __syncthreads();
  int C2 = (pos_sh > C2CAP) ? C2CAP : pos_sh;
  // ---- exact rank-select on C2 entries (broadcast LDS reads) ----
  if (C2 > ktop){
    for (int j = t; j < C2; j += 1024){
      float sj = s2[j];
      int g = 0, e = 0;
      for (int k2 = 0; k2 < C2; ++k2){
        float sk = s2[k2];
        g += (sk > sj);
        e += (sk == sj);
      }
      if (g < ktop && g + e >= ktop) thr_sh = sj;   // all writers same value
    }
  }
  __syncthreads();
  float s_thr = thr_sh;
  float part = 0.f;
  for (int j = t; j < C2; j += 1024){
    float sj = s2[j];
    if (sj >= s_thr) part += expf(sj);
  }
  #pragma unroll
  for (int off = 32; off; off >>= 1) part += __shfl_xor(part, off, 64);
  if (lane == 0) wred[wave] = part;
  __syncthreads();
  if (t == 0){
    float T = 0.f;
    for (int w = 0; w < 16; ++w) T += wred[w];
    lnD_sh = logf(T + 1e-10f * Z_sh);          // D = Z*(sum_top p + 1e-10)
  }
  __syncthreads();
  float lnD = lnD_sh;
  for (int j = t; j < C2; j += 1024){          // rewrite included entries
    float sj = s2[j];
    if (sj >= s_thr) out[i2[j]] = logf(expf(sj - lnD) + 1e-10f);
  }
  float bestv = NEG_INF, bestlogit = NEG_INF;  // gumbel categorical
  unsigned int bestidx = 0xFFFFFFFFu;
  for (int j = t; j < C2; j += 1024){
    float sj = s2[j];
    if (sj >= s_thr){
      unsigned int idx = i2[j];
      float logit = sj - lnD;                  // log(filtered)
      float val = logit + gumbel_from_idx(idx);
      if (val > bestv || (val == bestv && idx < bestidx)){
        bestv = val; bestlogit = logit; bestidx = idx;
      }
    }
  }
  #pragma unroll
  for (int off = 32; off; off >>= 1){
    float ov = __shfl_xor(bestv, off, 64);
    float ol = __shfl_xor(bestlogit, off, 64);
    unsigned int oi = (unsigned int)__shfl_xor((int)bestidx, off, 64);
    if (ov > bestv || (ov == bestv && oi < bestidx)){
      bestv = ov; bestlogit = ol; bestidx = oi;
    }
  }
  if (lane == 0){ rv[wave] = bestv; rl[wave] = bestlogit; ri[wave] = bestidx; }
  __syncthreads();
  if (t == 0){
    for (int w = 1; w < 16; ++w){
      if (rv[w] > rv[0] || (rv[w] == rv[0] && ri[w] < ri[0])){
        rv[0] = rv[w]; rl[0] = rl[w]; ri[0] = ri[w];
      }
    }
    out[N] = rl[0];                 // log_prob_action
    out[N + 1] = (float)ri[0];      // action_idx
  }
}

extern "C" void kernel_launch(void* const* d_in, const int* in_sizes, int n_in,
                              void* d_out, int out_size, void* d_ws, size_t ws_size,
                              hipStream_t stream){
  const float* cur  = (const float*)d_in[0];
  const float* ctx  = (const float*)d_in[1];
  const float* cand = (const float*)d_in[2];
  const float* Wq   = (const float*)d_in[3];
  const float* Wk   = (const float*)d_in[4];
  const int*   mask = (const int*)d_in[5];
  int N = in_sizes[5];
  float* out = (float*)d_out;

  char* ws = (char*)d_ws;
  unsigned int* scal_u  = (unsigned int*)ws;                  // 64B ([8]=done)
  float*        v       = (float*)(ws + 512);                 // 512B
  float*        zpart   = (float*)(ws + 1024);                // MAXB*4
  unsigned int* cnt     = (unsigned int*)(ws + 1536);         // MAXB*4
  unsigned int* hist    = (unsigned int*)(ws + 4096);         // 8KB
  float*        scores  = (float*)(ws + 16384);               // N*4, 16B-aligned
  char*         bufbase = ws + 16384 + (((size_t)N * 4 + 255) & ~255ull);
  float*        buf_s   = (float*)bufbase;                    // MAXB*SLOT*4 = 1MB
  unsigned int* buf_idx = (unsigned int*)(bufbase + (size_t)MAXB * SLOT * 4);

  int ktop = N / 2; if (ktop < 1) ktop = 1; if (ktop > 50) ktop = 50;
  int g_score = (N + 63) / 64;          // one 64-row tile per block
  int nb = (N + 4095) / 4096;           // 49 for N=200000
  if (nb > MAXB) nb = MAXB;             // (N fixed at 200000; guard only)

  k_prep<<<1, 256, 0, stream>>>(cur, ctx, Wq, Wk, v, hist, scal_u);
  k_score<<<g_score, 256, 0, stream>>>(cand, mask, v, scores, out, N);
  k_tail<<<nb, 1024, 0, stream>>>(scores, scal_u, hist, zpart, cnt,
                                  buf_idx, buf_s, out, N, ktop, nb);
}

// Round 8
// 205.805 us; speedup vs baseline: 1.2038x; 1.0018x over previous
//
#include <hip/hip_runtime.h>
#include <math.h>

// AttentionDecoder R15: 2 kernels.
// score (FUSED: every block computes v redundantly -- no flag/no spin, the
//   R10 disaster was the spin not the recompute; deterministic bit-identical
//   v per block. Mask loads issued first, MLP overlaps their latency, cand
//   row loads exec-masked on mask!=0 -> ~51MB instead of 102MB) |
// tail (R14's proven 49-block hist/gather + pipelined fin, byte-identical).
// Blocks 1..8 of score zero global hist, block 9 zeroes scal (stream order
// puts these before k_tail). Model: F~115us fixed fills in timed region,
// L~10us/launch, tail~30us. Cut 3 launches -> 2, halve score BW demand.

#define SLOT 4096
#define MAXB 64
#define C2CAP 2048
#define NEG_INF (-__builtin_inff())

// order-preserving float->uint mapping (monotone increasing)
__device__ __forceinline__ unsigned int f2ord(float f){
  unsigned int b = __float_as_uint(f);
  return (b & 0x80000000u) ? ~b : (b | 0x80000000u);
}
__device__ __forceinline__ unsigned int rotl32(unsigned int x, int d){
  return (x << d) | (x >> (32 - d));
}

// JAX partitionable threefry, key (0,42): x0=idx>>32(=0), x1=idx; bits=w0^w1.
// gumbel = -log(-log(u)), u = bitcast((bits>>9)|0x3f800000)-1 clamped to tiny.
__device__ float gumbel_from_idx(unsigned int idx){
  unsigned int x0 = 0u, x1 = idx;
  const unsigned int ks0 = 0u, ks1 = 42u;
  const unsigned int ks2 = 0u ^ 42u ^ 0x1BD11BDAu;
  x0 += ks0; x1 += ks1;
#define TF_RND(r) { x0 += x1; x1 = rotl32(x1, (r)); x1 ^= x0; }
  TF_RND(13) TF_RND(15) TF_RND(26) TF_RND(6)
  x0 += ks1; x1 += ks2 + 1u;
  TF_RND(17) TF_RND(29) TF_RND(16) TF_RND(24)
  x0 += ks2; x1 += ks0 + 2u;
  TF_RND(13) TF_RND(15) TF_RND(26) TF_RND(6)
  x0 += ks0; x1 += ks1 + 3u;
  TF_RND(17) TF_RND(29) TF_RND(16) TF_RND(24)
  x0 += ks1; x1 += ks2 + 4u;
  TF_RND(13) TF_RND(15) TF_RND(26) TF_RND(6)
  x0 += ks2; x1 += ks0 + 5u;
#undef TF_RND
  unsigned int bits = x0 ^ x1;
  unsigned int fb = (bits >> 9) | 0x3f800000u;
  float f = __uint_as_float(fb) - 1.0f;
  float u = (f < 1.17549435e-38f) ? 1.17549435e-38f : f;
  return -logf(-logf(u));
}

// lh[2048] counts -> *u_lo_sh = lower edge of the bin where cumulative-from-
// top first reaches ktop (0 if never). Caller sets *csel_sh=-1 + sync before.
// All 1024 threads must call (uniform). lh is not modified.
__device__ void hist_select(unsigned int* lh, unsigned int* suf, int* csel_sh,
                            unsigned int* u_lo_sh, int ktop, int t){
  if (t < 256){
    unsigned int csum = 0;
    #pragma unroll
    for (int k = 0; k < 8; ++k) csum += lh[t * 8 + k];
    suf[t] = csum;
  }
  __syncthreads();
  for (int d = 1; d < 256; d <<= 1){
    unsigned int add = 0u;
    if (t < 256 && t + d < 256) add = suf[t + d];
    __syncthreads();
    if (t < 256) suf[t] += add;
    __syncthreads();
  }
  if (t < 256){
    unsigned int st = suf[t];
    unsigned int sn = (t < 255) ? suf[t + 1] : 0u;
    if (st >= (unsigned)ktop && sn < (unsigned)ktop) *csel_sh = t;   // unique
  }
  __syncthreads();
  if (t == 0){
    int b_sel = 0;
    int c = *csel_sh;
    if (c >= 0){
      unsigned int cum = (c < 255) ? suf[c + 1] : 0u;
      for (int bi = 8 * c + 7; bi >= 8 * c; --bi){
        cum += lh[bi];
        if (cum >= (unsigned)ktop){ b_sel = bi; break; }
      }
    }
    *u_lo_sh = ((unsigned int)b_sel) << 21;
  }
  __syncthreads();
}

// FUSED score: every block computes v = Wk^T(Wq [cur;ctx]) itself (identical
// op order -> bit-identical across blocks), then the proven GEMV core.
// Mask loads issued before the MLP so their latency hides under it; cand
// row loads exec-masked on mask!=0 (half-wave uniform -> no divergence).
__global__ __launch_bounds__(256) void k_score(const float* __restrict__ cur,
    const float* __restrict__ ctx, const float* __restrict__ Wq,
    const float* __restrict__ Wk, const float* __restrict__ cand,
    const int* __restrict__ mask, unsigned int* __restrict__ hist,
    unsigned int* __restrict__ scal_u, float* __restrict__ scores,
    float* __restrict__ out, int N){
  const float NLOG = logf(1e-10f);
  __shared__ float q[128];
  __shared__ float vpart[256];
  __shared__ float vsh[128];
  int t = threadIdx.x;
  int lane = t & 63, wave = t >> 6;
  int hi = lane >> 5, hl = lane & 31;
  int base = (blockIdx.x * 4 + wave) * 16;
  // ---- issue mask loads first (latency hides under MLP) ----
  int m[8];
  #pragma unroll
  for (int k = 0; k < 8; ++k){
    int r = base + 2 * k + hi;
    r = (r < N) ? r : (N - 1);
    m[k] = mask[r];
  }
  // ---- housekeeping for k_tail (stream order: lands before tail launch) ----
  if (gridDim.x >= 16){
    if (blockIdx.x >= 1 && blockIdx.x <= 8) hist[(blockIdx.x - 1) * 256 + t] = 0u;
    if (blockIdx.x == 9 && t < 16) scal_u[t] = 0u;
  } else if (blockIdx.x == 0){
    for (int k = t; k < 2048; k += 256) hist[k] = 0u;
    if (t < 16) scal_u[t] = 0u;
  }
  // ---- redundant per-block MLP (R8-proven wave-parallel form) ----
  {
    float4 cb0 = ((const float4*)cur)[hl];
    float4 cb1 = ((const float4*)ctx)[hl];
    const float4* Wq4 = (const float4*)Wq;
    #pragma unroll 4
    for (int i = 0; i < 16; ++i){
      int row = wave * 32 + 2 * i + hi;        // 4 waves x 16 x 2 rows = 128
      float4 w0 = Wq4[row * 64 + hl];          // coalesced 512B per half-wave
      float4 w1 = Wq4[row * 64 + 32 + hl];
      float d = fmaf(w0.x, cb0.x, fmaf(w0.y, cb0.y, fmaf(w0.z, cb0.z, w0.w * cb0.w)));
      d = fmaf(w1.x, cb1.x, fmaf(w1.y, cb1.y, fmaf(w1.z, cb1.z, fmaf(w1.w, cb1.w, d))));
      d += __shfl_xor(d, 1, 64);
      d += __shfl_xor(d, 2, 64);
      d += __shfl_xor(d, 4, 64);
      d += __shfl_xor(d, 8, 64);
      d += __shfl_xor(d, 16, 64);
      if (hl == 0) q[row] = d;
    }
    __syncthreads();
    int col = t & 127, half = t >> 7;
    const float* wkp = Wk + half * 64 * 128 + col;
    const float* qp  = q + half * 64;
    float acc = 0.f;
    #pragma unroll 8
    for (int h = 0; h < 64; ++h) acc = fmaf(qp[h], wkp[h * 128], acc);
    vpart[t] = acc;
    __syncthreads();
    if (t < 128) vsh[t] = vpart[t] + vpart[t + 128];
    __syncthreads();
  }
  float4 v4 = ((const float4*)vsh)[hl];
  // ---- masked cand loads (8 in flight for active rows) ----
  float4 c[8];
  #pragma unroll
  for (int k = 0; k < 8; ++k){
    int r = base + 2 * k + hi;
    r = (r < N) ? r : (N - 1);                 // clamp keeps addr valid
    c[k] = make_float4(0.f, 0.f, 0.f, 0.f);
    if (m[k]) c[k] = ((const float4*)cand)[(size_t)r * 32 + hl];
  }
  float p[8];
  #pragma unroll
  for (int k = 0; k < 8; ++k)                  // consume
    p[k] = fmaf(c[k].x, v4.x, fmaf(c[k].y, v4.y, fmaf(c[k].z, v4.z, c[k].w * v4.w)));
  #pragma unroll
  for (int k = 0; k < 8; ++k){                 // 8 independent 5-shfl chains
    p[k] += __shfl_xor(p[k], 1, 64);
    p[k] += __shfl_xor(p[k], 2, 64);
    p[k] += __shfl_xor(p[k], 4, 64);
    p[k] += __shfl_xor(p[k], 8, 64);
    p[k] += __shfl_xor(p[k], 16, 64);
  }
  float sv = p[0];
  #pragma unroll
  for (int k = 1; k < 8; ++k) sv = (hl == k) ? p[k] : sv;
  if (hl < 8){                                 // writer lanes
    int r = base + 2 * hl + hi;
    if (r < N) scores[r] = mask[r] ? sv : NEG_INF;
  }
  if (t < 16){                                 // default output value, float4
    int o4 = blockIdx.x * 16 + t;
    if (o4 * 4 + 3 < N){
      ((float4*)out)[o4] = make_float4(NLOG, NLOG, NLOG, NLOG);
    } else {
      #pragma unroll
      for (int e = 0; e < 4; ++e){ int i = o4 * 4 + e; if (i < N) out[i] = NLOG; }
    }
  }
}

// Single tail launch, nb (<=49) blocks x 1024 thr, no polling, drop-free.
// (Byte-identical to R14's proven k_tail.)
__global__ __launch_bounds__(1024) void k_tail(const float* __restrict__ scores,
    unsigned int* __restrict__ scal_u, unsigned int* __restrict__ hist,
    float* __restrict__ zpart, unsigned int* __restrict__ cnt,
    unsigned int* __restrict__ buf_idx, float* __restrict__ buf_s,
    float* __restrict__ out, int N, int ktop, int nb){
  __shared__ unsigned int lh[2048];
  __shared__ unsigned int suf[256];
  __shared__ float s2[C2CAP];
  __shared__ unsigned int i2[C2CAP];
  __shared__ unsigned int cnt_l[MAXB], offs[MAXB];
  __shared__ float wred[16];
  __shared__ float rv[16], rl[16];
  __shared__ unsigned int ri[16];
  __shared__ float Z_sh, thr_sh, lnD_sh;
  __shared__ unsigned int u_lo_sh;
  __shared__ int csel_sh, pos_sh, C_sh, last_sh;
  int t = threadIdx.x, b = blockIdx.x;
  int lane = t & 63, wave = t >> 6;
  for (int k = t; k < 2048; k += 1024) lh[k] = 0u;
  if (t == 0){ pos_sh = 0; csel_sh = -1; }
  __syncthreads();
  // ---- phase 1: chunk -> REGISTERS, local hist, Z partial ----
  int base = b * 4096;
  int i0 = base + 4 * t;
  float4 s4 = make_float4(NEG_INF, NEG_INF, NEG_INF, NEG_INF);
  if (i0 + 3 < N) s4 = ((const float4*)scores)[(base >> 2) + t];
  else {
    if (i0     < N) s4.x = scores[i0];
    if (i0 + 1 < N) s4.y = scores[i0 + 1];
    if (i0 + 2 < N) s4.z = scores[i0 + 2];
  }
  float ez = 0.f;
#define HVISIT(s_) { float sx = (s_); if (sx > NEG_INF){ \
    atomicAdd(&lh[f2ord(sx) >> 21], 1u); ez += expf(sx); } }
  HVISIT(s4.x) HVISIT(s4.y) HVISIT(s4.z) HVISIT(s4.w)
#undef HVISIT
  #pragma unroll
  for (int off = 32; off; off >>= 1) ez += __shfl_xor(ez, off, 64);
  if (lane == 0) wred[wave] = ez;
  __syncthreads();                             // lh + wred complete
  // ---- phase 2: LOCAL suffix scan -> local top-ktop bin edge ----
  hist_select(lh, suf, &csel_sh, &u_lo_sh, ktop, t);
  // ---- phase 3: gather local superset (SLOT = chunk size: never drops),
  //      and flush LDS hist -> global hist (chains <= nb) ----
  unsigned int u_lo = u_lo_sh;
#define GVISIT(s_, i_) { float sx = (s_); \
    if (sx > NEG_INF && f2ord(sx) >= u_lo && (i_) < N){ \
      int p = atomicAdd(&pos_sh, 1); \
      buf_s[(size_t)b * SLOT + p] = sx; \
      buf_idx[(size_t)b * SLOT + p] = (unsigned int)(i_); } }
  GVISIT(s4.x, i0) GVISIT(s4.y, i0 + 1) GVISIT(s4.z, i0 + 2) GVISIT(s4.w, i0 + 3)
#undef GVISIT
  for (int k = t; k < 2048; k += 1024){
    unsigned int cc = lh[k];
    if (cc) atomicAdd(&hist[k], cc);
  }
  __syncthreads();                             // drains buf stores + hist atomics
  if (t == 0){
    cnt[b] = (unsigned int)pos_sh;
    float z = 0.f;
    for (int w = 0; w < 16; ++w) z += wred[w];
    zpart[b] = z;
    __threadfence();
    unsigned int old = atomicAdd(&scal_u[8], 1u);   // single-shot, chain <= nb
    last_sh = (old == (unsigned)(nb - 1));
  }
  __syncthreads();
  if (!last_sh) return;
  __threadfence();
  // ---- fin (last block only): all global reads independent + pipelined ----
  if (t < nb) cnt_l[t] = cnt[t];
  for (int k = t; k < 2048; k += 1024) lh[k] = hist[k];   // coalesced, 2 iters
  {
    float z = 0.f;
    if (t < 64){
      z = (t < nb) ? zpart[t] : 0.f;
      #pragma unroll
      for (int off = 32; off; off >>= 1) z += __shfl_xor(z, off, 64);
    }
    if (t == 0){ Z_sh = z; thr_sh = NEG_INF; pos_sh = 0; csel_sh = -1; }
  }
  __syncthreads();
  if (t == 0){
    unsigned int acc = 0;
    for (int b2 = 0; b2 < nb; ++b2){ offs[b2] = acc; acc += cnt_l[b2]; }
    C_sh = (int)acc;
  }
  __syncthreads();
  // global v50 bin edge from the FULL global hist (R7 semantics)
  hist_select(lh, suf, &csel_sh, &u_lo_sh, ktop, t);
  unsigned int u_lo2 = u_lo_sh;
  int C = C_sh;
  // indexed compact sweep: p -> (block, j) via LDS binary search; all loads
  // independent across p-iterations (C ~ 3.2k -> ~4 strided iterations)
  for (int p = t; p < C; p += 1024){
    int lo = 0, hi2 = nb - 1;
    while (lo < hi2){
      int mid = (lo + hi2 + 1) >> 1;
      if (offs[mid] <= (unsigned)p) lo = mid; else hi2 = mid - 1;
    }
    unsigned int j = (unsigned)p - offs[lo];
    float sx = buf_s[(size_t)lo * SLOT + j];
    if (sx > NEG_INF && f2ord(sx) >= u_lo2){
      int q = atomicAdd(&pos_sh, 1);
      if (q < C2CAP){ s2[q] = sx; i2[q] = buf_idx[(size_t)lo * SLOT + j]; }
    }
  }
  __syncthreads();
  int C2 = (pos_sh > C2CAP) ? C2CAP : pos_sh;
  // ---- exact rank-select on C2 entries (broadcast LDS reads) ----
  if (C2 > ktop){
    for (int j = t; j < C2; j += 1024){
      float sj = s2[j];
      int g = 0, e = 0;
      for (int k2 = 0; k2 < C2; ++k2){
        float sk = s2[k2];
        g += (sk > sj);
        e += (sk == sj);
      }
      if (g < ktop && g + e >= ktop) thr_sh = sj;   // all writers same value
    }
  }
  __syncthreads();
  float s_thr = thr_sh;
  float part = 0.f;
  for (int j = t; j < C2; j += 1024){
    float sj = s2[j];
    if (sj >= s_thr) part += expf(sj);
  }
  #pragma unroll
  for (int off = 32; off; off >>= 1) part += __shfl_xor(part, off, 64);
  if (lane == 0) wred[wave] = part;
  __syncthreads();
  if (t == 0){
    float T = 0.f;
    for (int w = 0; w < 16; ++w) T += wred[w];
    lnD_sh = logf(T + 1e-10f * Z_sh);          // D = Z*(sum_top p + 1e-10)
  }
  __syncthreads();
  float lnD = lnD_sh;
  for (int j = t; j < C2; j += 1024){          // rewrite included entries
    float sj = s2[j];
    if (sj >= s_thr) out[i2[j]] = logf(expf(sj - lnD) + 1e-10f);
  }
  float bestv = NEG_INF, bestlogit = NEG_INF;  // gumbel categorical
  unsigned int bestidx = 0xFFFFFFFFu;
  for (int j = t; j < C2; j += 1024){
    float sj = s2[j];
    if (sj >= s_thr){
      unsigned int idx = i2[j];
      float logit = sj - lnD;                  // log(filtered)
      float val = logit + gumbel_from_idx(idx);
      if (val > bestv || (val == bestv && idx < bestidx)){
        bestv = val; bestlogit = logit; bestidx = idx;
      }
    }
  }
  #pragma unroll
  for (int off = 32; off; off >>= 1){
    float ov = __shfl_xor(bestv, off, 64);
    float ol = __shfl_xor(bestlogit, off, 64);
    unsigned int oi = (unsigned int)__shfl_xor((int)bestidx, off, 64);
    if (ov > bestv || (ov == bestv && oi < bestidx)){
      bestv = ov; bestlogit = ol; bestidx = oi;
    }
  }
  if (lane == 0){ rv[wave] = bestv; rl[wave] = bestlogit; ri[wave] = bestidx; }
  __syncthreads();
  if (t == 0){
    for (int w = 1; w < 16; ++w){
      if (rv[w] > rv[0] || (rv[w] == rv[0] && ri[w] < ri[0])){
        rv[0] = rv[w]; rl[0] = rl[w]; ri[0] = ri[w];
      }
    }
    out[N] = rl[0];                 // log_prob_action
    out[N + 1] = (float)ri[0];      // action_idx
  }
}

extern "C" void kernel_launch(void* const* d_in, const int* in_sizes, int n_in,
                              void* d_out, int out_size, void* d_ws, size_t ws_size,
                              hipStream_t stream){
  const float* cur  = (const float*)d_in[0];
  const float* ctx  = (const float*)d_in[1];
  const float* cand = (const float*)d_in[2];
  const float* Wq   = (const float*)d_in[3];
  const float* Wk   = (const float*)d_in[4];
  const int*   mask = (const int*)d_in[5];
  int N = in_sizes[5];
  float* out = (float*)d_out;

  char* ws = (char*)d_ws;
  unsigned int* scal_u  = (unsigned int*)ws;                  // 64B ([8]=done)
  float*        zpart   = (float*)(ws + 1024);                // MAXB*4
  unsigned int* cnt     = (unsigned int*)(ws + 1536);         // MAXB*4
  unsigned int* hist    = (unsigned int*)(ws + 4096);         // 8KB
  float*        scores  = (float*)(ws + 16384);               // N*4, 16B-aligned
  char*         bufbase = ws + 16384 + (((size_t)N * 4 + 255) & ~255ull);
  float*        buf_s   = (float*)bufbase;                    // MAXB*SLOT*4 = 1MB
  unsigned int* buf_idx = (unsigned int*)(bufbase + (size_t)MAXB * SLOT * 4);

  int ktop = N / 2; if (ktop < 1) ktop = 1; if (ktop > 50) ktop = 50;
  int g_score = (N + 63) / 64;          // one 64-row tile per block
  int nb = (N + 4095) / 4096;           // 49 for N=200000
  if (nb > MAXB) nb = MAXB;             // (N fixed at 200000; guard only)

  k_score<<<g_score, 256, 0, stream>>>(cur, ctx, Wq, Wk, cand, mask,
                                       hist, scal_u, scores, out, N);
  k_tail<<<nb, 1024, 0, stream>>>(scores, scal_u, hist, zpart, cnt,
                                  buf_idx, buf_s, out, N, ktop, nb);
}

// Round 10
// 196.833 us; speedup vs baseline: 1.2587x; 1.0456x over previous
//
#include <hip/hip_runtime.h>
#include <math.h>

// AttentionDecoder R16 (resubmit -- prior run died on container acquisition,
// not on the kernel). 2 kernels.
// score (FUSED, 256 rows/block, grid 782): redundant per-block MLP cost is
//   L2 BW (192KB/block) -> 4x fewer blocks = 600->150MB L2 traffic (~-12us,
//   the R15 lesson: price redundant work in BYTES not FLOPs). Mask loads
//   first (latency under MLP), cand loads exec-masked (~51MB), 2 batches of
//   16 row-pairs per wave (c[16] in flight, VGPR~110, 4 waves/SIMD).
// tail (R14's proven 49-block hist/gather + pipelined fin, byte-identical).
// Model: F~125us harness re-poison fills in timed region (untouchable),
// L~10us/launch. If this round lands >=203us the controllable budget is
// exhausted -> declare roofline.

#define SLOT 4096
#define MAXB 64
#define C2CAP 2048
#define NEG_INF (-__builtin_inff())

// order-preserving float->uint mapping (monotone increasing)
__device__ __forceinline__ unsigned int f2ord(float f){
  unsigned int b = __float_as_uint(f);
  return (b & 0x80000000u) ? ~b : (b | 0x80000000u);
}
__device__ __forceinline__ unsigned int rotl32(unsigned int x, int d){
  return (x << d) | (x >> (32 - d));
}

// JAX partitionable threefry, key (0,42): x0=idx>>32(=0), x1=idx; bits=w0^w1.
// gumbel = -log(-log(u)), u = bitcast((bits>>9)|0x3f800000)-1 clamped to tiny.
__device__ float gumbel_from_idx(unsigned int idx){
  unsigned int x0 = 0u, x1 = idx;
  const unsigned int ks0 = 0u, ks1 = 42u;
  const unsigned int ks2 = 0u ^ 42u ^ 0x1BD11BDAu;
  x0 += ks0; x1 += ks1;
#define TF_RND(r) { x0 += x1; x1 = rotl32(x1, (r)); x1 ^= x0; }
  TF_RND(13) TF_RND(15) TF_RND(26) TF_RND(6)
  x0 += ks1; x1 += ks2 + 1u;
  TF_RND(17) TF_RND(29) TF_RND(16) TF_RND(24)
  x0 += ks2; x1 += ks0 + 2u;
  TF_RND(13) TF_RND(15) TF_RND(26) TF_RND(6)
  x0 += ks0; x1 += ks1 + 3u;
  TF_RND(17) TF_RND(29) TF_RND(16) TF_RND(24)
  x0 += ks1; x1 += ks2 + 4u;
  TF_RND(13) TF_RND(15) TF_RND(26) TF_RND(6)
  x0 += ks2; x1 += ks0 + 5u;
#undef TF_RND
  unsigned int bits = x0 ^ x1;
  unsigned int fb = (bits >> 9) | 0x3f800000u;
  float f = __uint_as_float(fb) - 1.0f;
  float u = (f < 1.17549435e-38f) ? 1.17549435e-38f : f;
  return -logf(-logf(u));
}

// lh[2048] counts -> *u_lo_sh = lower edge of the bin where cumulative-from-
// top first reaches ktop (0 if never). Caller sets *csel_sh=-1 + sync before.
// All 1024 threads must call (uniform). lh is not modified.
__device__ void hist_select(unsigned int* lh, unsigned int* suf, int* csel_sh,
                            unsigned int* u_lo_sh, int ktop, int t){
  if (t < 256){
    unsigned int csum = 0;
    #pragma unroll
    for (int k = 0; k < 8; ++k) csum += lh[t * 8 + k];
    suf[t] = csum;
  }
  __syncthreads();
  for (int d = 1; d < 256; d <<= 1){
    unsigned int add = 0u;
    if (t < 256 && t + d < 256) add = suf[t + d];
    __syncthreads();
    if (t < 256) suf[t] += add;
    __syncthreads();
  }
  if (t < 256){
    unsigned int st = suf[t];
    unsigned int sn = (t < 255) ? suf[t + 1] : 0u;
    if (st >= (unsigned)ktop && sn < (unsigned)ktop) *csel_sh = t;   // unique
  }
  __syncthreads();
  if (t == 0){
    int b_sel = 0;
    int c = *csel_sh;
    if (c >= 0){
      unsigned int cum = (c < 255) ? suf[c + 1] : 0u;
      for (int bi = 8 * c + 7; bi >= 8 * c; --bi){
        cum += lh[bi];
        if (cum >= (unsigned)ktop){ b_sel = bi; break; }
      }
    }
    *u_lo_sh = ((unsigned int)b_sel) << 21;
  }
  __syncthreads();
}

// FUSED score, 256 rows/block. Every block computes v = Wk^T(Wq [cur;ctx])
// itself (identical op order -> bit-identical across blocks). Mask bits
// loaded first (latency hides under MLP); per wave 2 batches x 16 row-pairs,
// cand row loads exec-masked on mask!=0 (half-wave uniform, no divergence).
__global__ __launch_bounds__(256) void k_score(const float* __restrict__ cur,
    const float* __restrict__ ctx, const float* __restrict__ Wq,
    const float* __restrict__ Wk, const float* __restrict__ cand,
    const int* __restrict__ mask, unsigned int* __restrict__ hist,
    unsigned int* __restrict__ scal_u, float* __restrict__ scores,
    float* __restrict__ out, int N){
  const float NLOG = logf(1e-10f);
  __shared__ float q[128];
  __shared__ float vpart[256];
  __shared__ float vsh[128];
  int t = threadIdx.x;
  int lane = t & 63, wave = t >> 6;
  int hi = lane >> 5, hl = lane & 31;
  int rowbase0 = blockIdx.x * 256 + wave * 64;     // 64 rows per wave
  // ---- mask bits first (32 loads in flight; latency hides under MLP) ----
  unsigned int m_bits = 0u;
  #pragma unroll
  for (int ib = 0; ib < 2; ++ib){
    #pragma unroll
    for (int k = 0; k < 16; ++k){
      int r = rowbase0 + ib * 32 + 2 * k + hi;
      r = (r < N) ? r : (N - 1);
      if (mask[r]) m_bits |= (1u << (ib * 16 + k));
    }
  }
  // ---- housekeeping for k_tail (stream order: lands before tail launch) ----
  if (blockIdx.x >= 1 && blockIdx.x <= 8) hist[(blockIdx.x - 1) * 256 + t] = 0u;
  if (blockIdx.x == 9 && t < 16) scal_u[t] = 0u;
  // ---- redundant per-block MLP (R8-proven wave-parallel form) ----
  {
    float4 cb0 = ((const float4*)cur)[hl];
    float4 cb1 = ((const float4*)ctx)[hl];
    const float4* Wq4 = (const float4*)Wq;
    #pragma unroll 4
    for (int i = 0; i < 16; ++i){
      int row = wave * 32 + 2 * i + hi;        // 4 waves x 16 x 2 rows = 128
      float4 w0 = Wq4[row * 64 + hl];          // coalesced 512B per half-wave
      float4 w1 = Wq4[row * 64 + 32 + hl];
      float d = fmaf(w0.x, cb0.x, fmaf(w0.y, cb0.y, fmaf(w0.z, cb0.z, w0.w * cb0.w)));
      d = fmaf(w1.x, cb1.x, fmaf(w1.y, cb1.y, fmaf(w1.z, cb1.z, fmaf(w1.w, cb1.w, d))));
      d += __shfl_xor(d, 1, 64);
      d += __shfl_xor(d, 2, 64);
      d += __shfl_xor(d, 4, 64);
      d += __shfl_xor(d, 8, 64);
      d += __shfl_xor(d, 16, 64);
      if (hl == 0) q[row] = d;
    }
    __syncthreads();
    int col = t & 127, half = t >> 7;
    const float* wkp = Wk + half * 64 * 128 + col;
    const float* qp  = q + half * 64;
    float acc = 0.f;
    #pragma unroll 8
    for (int h = 0; h < 64; ++h) acc = fmaf(qp[h], wkp[h * 128], acc);
    vpart[t] = acc;
    __syncthreads();
    if (t < 128) vsh[t] = vpart[t] + vpart[t + 128];
    __syncthreads();
  }
  float4 v4 = ((const float4*)vsh)[hl];
  const float4* cp = (const float4*)cand;
  // ---- 2 batches x 16 row-pairs (16 masked loads in flight per batch) ----
  #pragma unroll 1
  for (int ib = 0; ib < 2; ++ib){
    int rb = rowbase0 + ib * 32;
    float4 c[16];
    #pragma unroll
    for (int k = 0; k < 16; ++k){
      int r = rb + 2 * k + hi;
      r = (r < N) ? r : (N - 1);               // clamp keeps addr valid
      c[k] = make_float4(0.f, 0.f, 0.f, 0.f);
      if ((m_bits >> (ib * 16 + k)) & 1u) c[k] = cp[(size_t)r * 32 + hl];
    }
    float p[16];
    #pragma unroll
    for (int k = 0; k < 16; ++k)               // consume
      p[k] = fmaf(c[k].x, v4.x, fmaf(c[k].y, v4.y, fmaf(c[k].z, v4.z, c[k].w * v4.w)));
    #pragma unroll
    for (int k = 0; k < 16; ++k){              // 16 independent 5-shfl chains
      p[k] += __shfl_xor(p[k], 1, 64);
      p[k] += __shfl_xor(p[k], 2, 64);
      p[k] += __shfl_xor(p[k], 4, 64);
      p[k] += __shfl_xor(p[k], 8, 64);
      p[k] += __shfl_xor(p[k], 16, 64);
    }
    float sv = p[0];
    #pragma unroll
    for (int k = 1; k < 16; ++k) sv = (hl == k) ? p[k] : sv;
    if (hl < 16){                              // writer lanes
      int r = rb + 2 * hl + hi;
      if (r < N) scores[r] = ((m_bits >> (ib * 16 + hl)) & 1u) ? sv : NEG_INF;
    }
  }
  if (t < 64){                                 // default output value, float4
    int o4 = blockIdx.x * 64 + t;
    if (o4 * 4 + 3 < N){
      ((float4*)out)[o4] = make_float4(NLOG, NLOG, NLOG, NLOG);
    } else {
      #pragma unroll
      for (int e = 0; e < 4; ++e){ int i = o4 * 4 + e; if (i < N) out[i] = NLOG; }
    }
  }
}

// Single tail launch, nb (<=49) blocks x 1024 thr, no polling, drop-free.
// (Byte-identical to R14's proven k_tail.)
__global__ __launch_bounds__(1024) void k_tail(const float* __restrict__ scores,
    unsigned int* __restrict__ scal_u, unsigned int* __restrict__ hist,
    float* __restrict__ zpart, unsigned int* __restrict__ cnt,
    unsigned int* __restrict__ buf_idx, float* __restrict__ buf_s,
    float* __restrict__ out, int N, int ktop, int nb){
  __shared__ unsigned int lh[2048];
  __shared__ unsigned int suf[256];
  __shared__ float s2[C2CAP];
  __shared__ unsigned int i2[C2CAP];
  __shared__ unsigned int cnt_l[MAXB], offs[MAXB];
  __shared__ float wred[16];
  __shared__ float rv[16], rl[16];
  __shared__ unsigned int ri[16];
  __shared__ float Z_sh, thr_sh, lnD_sh;
  __shared__ unsigned int u_lo_sh;
  __shared__ int csel_sh, pos_sh, C_sh, last_sh;
  int t = threadIdx.x, b = blockIdx.x;
  int lane = t & 63, wave = t >> 6;
  for (int k = t; k < 2048; k += 1024) lh[k] = 0u;
  if (t == 0){ pos_sh = 0; csel_sh = -1; }
  __syncthreads();
  // ---- phase 1: chunk -> REGISTERS, local hist, Z partial ----
  int base = b * 4096;
  int i0 = base + 4 * t;
  float4 s4 = make_float4(NEG_INF, NEG_INF, NEG_INF, NEG_INF);
  if (i0 + 3 < N) s4 = ((const float4*)scores)[(base >> 2) + t];
  else {
    if (i0     < N) s4.x = scores[i0];
    if (i0 + 1 < N) s4.y = scores[i0 + 1];
    if (i0 + 2 < N) s4.z = scores[i0 + 2];
  }
  float ez = 0.f;
#define HVISIT(s_) { float sx = (s_); if (sx > NEG_INF){ \
    atomicAdd(&lh[f2ord(sx) >> 21], 1u); ez += expf(sx); } }
  HVISIT(s4.x) HVISIT(s4.y) HVISIT(s4.z) HVISIT(s4.w)
#undef HVISIT
  #pragma unroll
  for (int off = 32; off; off >>= 1) ez += __shfl_xor(ez, off, 64);
  if (lane == 0) wred[wave] = ez;
  __syncthreads();                             // lh + wred complete
  // ---- phase 2: LOCAL suffix scan -> local top-ktop bin edge ----
  hist_select(lh, suf, &csel_sh, &u_lo_sh, ktop, t);
  // ---- phase 3: gather local superset (SLOT = chunk size: never drops),
  //      and flush LDS hist -> global hist (chains <= nb) ----
  unsigned int u_lo = u_lo_sh;
#define GVISIT(s_, i_) { float sx = (s_); \
    if (sx > NEG_INF && f2ord(sx) >= u_lo && (i_) < N){ \
      int p = atomicAdd(&pos_sh, 1); \
      buf_s[(size_t)b * SLOT + p] = sx; \
      buf_idx[(size_t)b * SLOT + p] = (unsigned int)(i_); } }
  GVISIT(s4.x, i0) GVISIT(s4.y, i0 + 1) GVISIT(s4.z, i0 + 2) GVISIT(s4.w, i0 + 3)
#undef GVISIT
  for (int k = t; k < 2048; k += 1024){
    unsigned int cc = lh[k];
    if (cc) atomicAdd(&hist[k], cc);
  }
  __syncthreads();                             // drains buf stores + hist atomics
  if (t == 0){
    cnt[b] = (unsigned int)pos_sh;
    float z = 0.f;
    for (int w = 0; w < 16; ++w) z += wred[w];
    zpart[b] = z;
    __threadfence();
    unsigned int old = atomicAdd(&scal_u[8], 1u);   // single-shot, chain <= nb
    last_sh = (old == (unsigned)(nb - 1));
  }
  __syncthreads();
  if (!last_sh) return;
  __threadfence();
  // ---- fin (last block only): all global reads independent + pipelined ----
  if (t < nb) cnt_l[t] = cnt[t];
  for (int k = t; k < 2048; k += 1024) lh[k] = hist[k];   // coalesced, 2 iters
  {
    float z = 0.f;
    if (t < 64){
      z = (t < nb) ? zpart[t] : 0.f;
      #pragma unroll
      for (int off = 32; off; off >>= 1) z += __shfl_xor(z, off, 64);
    }
    if (t == 0){ Z_sh = z; thr_sh = NEG_INF; pos_sh = 0; csel_sh = -1; }
  }
  __syncthreads();
  if (t == 0){
    unsigned int acc = 0;
    for (int b2 = 0; b2 < nb; ++b2){ offs[b2] = acc; acc += cnt_l[b2]; }
    C_sh = (int)acc;
  }
  __syncthreads();
  // global v50 bin edge from the FULL global hist (R7 semantics)
  hist_select(lh, suf, &csel_sh, &u_lo_sh, ktop, t);
  unsigned int u_lo2 = u_lo_sh;
  int C = C_sh;
  // indexed compact sweep: p -> (block, j) via LDS binary search; all loads
  // independent across p-iterations (C ~ 3.2k -> ~4 strided iterations)
  for (int p = t; p < C; p += 1024){
    int lo = 0, hi2 = nb - 1;
    while (lo < hi2){
      int mid = (lo + hi2 + 1) >> 1;
      if (offs[mid] <= (unsigned)p) lo = mid; else hi2 = mid - 1;
    }
    unsigned int j = (unsigned)p - offs[lo];
    float sx = buf_s[(size_t)lo * SLOT + j];
    if (sx > NEG_INF && f2ord(sx) >= u_lo2){
      int q = atomicAdd(&pos_sh, 1);
      if (q < C2CAP){ s2[q] = sx; i2[q] = buf_idx[(size_t)lo * SLOT + j]; }
    }
  }
  __syncthreads();
  int C2 = (pos_sh > C2CAP) ? C2CAP : pos_sh;
  // ---- exact rank-select on C2 entries (broadcast LDS reads) ----
  if (C2 > ktop){
    for (int j = t; j < C2; j += 1024){
      float sj = s2[j];
      int g = 0, e = 0;
      for (int k2 = 0; k2 < C2; ++k2){
        float sk = s2[k2];
        g += (sk > sj);
        e += (sk == sj);
      }
      if (g < ktop && g + e >= ktop) thr_sh = sj;   // all writers same value
    }
  }
  __syncthreads();
  float s_thr = thr_sh;
  float part = 0.f;
  for (int j = t; j < C2; j += 1024){
    float sj = s2[j];
    if (sj >= s_thr) part += expf(sj);
  }
  #pragma unroll
  for (int off = 32; off; off >>= 1) part += __shfl_xor(part, off, 64);
  if (lane == 0) wred[wave] = part;
  __syncthreads();
  if (t == 0){
    float T = 0.f;
    for (int w = 0; w < 16; ++w) T += wred[w];
    lnD_sh = logf(T + 1e-10f * Z_sh);          // D = Z*(sum_top p + 1e-10)
  }
  __syncthreads();
  float lnD = lnD_sh;
  for (int j = t; j < C2; j += 1024){          // rewrite included entries
    float sj = s2[j];
    if (sj >= s_thr) out[i2[j]] = logf(expf(sj - lnD) + 1e-10f);
  }
  float bestv = NEG_INF, bestlogit = NEG_INF;  // gumbel categorical
  unsigned int bestidx = 0xFFFFFFFFu;
  for (int j = t; j < C2; j += 1024){
    float sj = s2[j];
    if (sj >= s_thr){
      unsigned int idx = i2[j];
      float logit = sj - lnD;                  // log(filtered)
      float val = logit + gumbel_from_idx(idx);
      if (val > bestv || (val == bestv && idx < bestidx)){
        bestv = val; bestlogit = logit; bestidx = idx;
      }
    }
  }
  #pragma unroll
  for (int off = 32; off; off >>= 1){
    float ov = __shfl_xor(bestv, off, 64);
    float ol = __shfl_xor(bestlogit, off, 64);
    unsigned int oi = (unsigned int)__shfl_xor((int)bestidx, off, 64);
    if (ov > bestv || (ov == bestv && oi < bestidx)){
      bestv = ov; bestlogit = ol; bestidx = oi;
    }
  }
  if (lane == 0){ rv[wave] = bestv; rl[wave] = bestlogit; ri[wave] = bestidx; }
  __syncthreads();
  if (t == 0){
    for (int w = 1; w < 16; ++w){
      if (rv[w] > rv[0] || (rv[w] == rv[0] && ri[w] < ri[0])){
        rv[0] = rv[w]; rl[0] = rl[w]; ri[0] = ri[w];
      }
    }
    out[N] = rl[0];                 // log_prob_action
    out[N + 1] = (float)ri[0];      // action_idx
  }
}

extern "C" void kernel_launch(void* const* d_in, const int* in_sizes, int n_in,
                              void* d_out, int out_size, void* d_ws, size_t ws_size,
                              hipStream_t stream){
  const float* cur  = (const float*)d_in[0];
  const float* ctx  = (const float*)d_in[1];
  const float* cand = (const float*)d_in[2];
  const float* Wq   = (const float*)d_in[3];
  const float* Wk   = (const float*)d_in[4];
  const int*   mask = (const int*)d_in[5];
  int N = in_sizes[5];
  float* out = (float*)d_out;

  char* ws = (char*)d_ws;
  unsigned int* scal_u  = (unsigned int*)ws;                  // 64B ([8]=done)
  float*        zpart   = (float*)(ws + 1024);                // MAXB*4
  unsigned int* cnt     = (unsigned int*)(ws + 1536);         // MAXB*4
  unsigned int* hist    = (unsigned int*)(ws + 4096);         // 8KB
  float*        scores  = (float*)(ws + 16384);               // N*4, 16B-aligned
  char*         bufbase = ws + 16384 + (((size_t)N * 4 + 255) & ~255ull);
  float*        buf_s   = (float*)bufbase;                    // MAXB*SLOT*4 = 1MB
  unsigned int* buf_idx = (unsigned int*)(bufbase + (size_t)MAXB * SLOT * 4);

  int ktop = N / 2; if (ktop < 1) ktop = 1; if (ktop > 50) ktop = 50;
  int g_score = (N + 255) / 256;        // 256 rows per block -> 782 blocks
  int nb = (N + 4095) / 4096;           // 49 for N=200000
  if (nb > MAXB) nb = MAXB;             // (N fixed at 200000; guard only)

  k_score<<<g_score, 256, 0, stream>>>(cur, ctx, Wq, Wk, cand, mask,
                                       hist, scal_u, scores, out, N);
  k_tail<<<nb, 1024, 0, stream>>>(scores, scal_u, hist, zpart, cnt,
                                  buf_idx, buf_s, out, N, ktop, nb);
}

// Round 11
// 191.439 us; speedup vs baseline: 1.2942x; 1.0282x over previous
//
#include <hip/hip_runtime.h>
#include <math.h>

// AttentionDecoder R17: 2 kernels.
// score (FUSED, 512 rows/block x 512 thr, grid 391): score is scheduling-
//   round bound (R16: 782 blocks = 3.05 rounds/CU). 391 blocks @ 2/CU =
//   fully co-resident => ~1 round; MLP L2 traffic 150->75MB. Per-wave cand
//   code identical to R16 (64 rows/wave); Wk GEMV run by threads 0-255 with
//   R16's exact code => bit-identical v (absmax-0.0 lineage preserved).
// tail (R14's proven 49-block hist/gather + pipelined fin, byte-identical).
// Model: F~145us fills+resets in timed region, L~10us/launch.
// Pre-commit: >=195us or absmax!=0 -> revert + declare roofline.

#define SLOT 4096
#define MAXB 64
#define C2CAP 2048
#define NEG_INF (-__builtin_inff())

// order-preserving float->uint mapping (monotone increasing)
__device__ __forceinline__ unsigned int f2ord(float f){
  unsigned int b = __float_as_uint(f);
  return (b & 0x80000000u) ? ~b : (b | 0x80000000u);
}
__device__ __forceinline__ unsigned int rotl32(unsigned int x, int d){
  return (x << d) | (x >> (32 - d));
}

// JAX partitionable threefry, key (0,42): x0=idx>>32(=0), x1=idx; bits=w0^w1.
// gumbel = -log(-log(u)), u = bitcast((bits>>9)|0x3f800000)-1 clamped to tiny.
__device__ float gumbel_from_idx(unsigned int idx){
  unsigned int x0 = 0u, x1 = idx;
  const unsigned int ks0 = 0u, ks1 = 42u;
  const unsigned int ks2 = 0u ^ 42u ^ 0x1BD11BDAu;
  x0 += ks0; x1 += ks1;
#define TF_RND(r) { x0 += x1; x1 = rotl32(x1, (r)); x1 ^= x0; }
  TF_RND(13) TF_RND(15) TF_RND(26) TF_RND(6)
  x0 += ks1; x1 += ks2 + 1u;
  TF_RND(17) TF_RND(29) TF_RND(16) TF_RND(24)
  x0 += ks2; x1 += ks0 + 2u;
  TF_RND(13) TF_RND(15) TF_RND(26) TF_RND(6)
  x0 += ks0; x1 += ks1 + 3u;
  TF_RND(17) TF_RND(29) TF_RND(16) TF_RND(24)
  x0 += ks1; x1 += ks2 + 4u;
  TF_RND(13) TF_RND(15) TF_RND(26) TF_RND(6)
  x0 += ks2; x1 += ks0 + 5u;
#undef TF_RND
  unsigned int bits = x0 ^ x1;
  unsigned int fb = (bits >> 9) | 0x3f800000u;
  float f = __uint_as_float(fb) - 1.0f;
  float u = (f < 1.17549435e-38f) ? 1.17549435e-38f : f;
  return -logf(-logf(u));
}

// lh[2048] counts -> *u_lo_sh = lower edge of the bin where cumulative-from-
// top first reaches ktop (0 if never). Caller sets *csel_sh=-1 + sync before.
// All 1024 threads must call (uniform). lh is not modified.
__device__ void hist_select(unsigned int* lh, unsigned int* suf, int* csel_sh,
                            unsigned int* u_lo_sh, int ktop, int t){
  if (t < 256){
    unsigned int csum = 0;
    #pragma unroll
    for (int k = 0; k < 8; ++k) csum += lh[t * 8 + k];
    suf[t] = csum;
  }
  __syncthreads();
  for (int d = 1; d < 256; d <<= 1){
    unsigned int add = 0u;
    if (t < 256 && t + d < 256) add = suf[t + d];
    __syncthreads();
    if (t < 256) suf[t] += add;
    __syncthreads();
  }
  if (t < 256){
    unsigned int st = suf[t];
    unsigned int sn = (t < 255) ? suf[t + 1] : 0u;
    if (st >= (unsigned)ktop && sn < (unsigned)ktop) *csel_sh = t;   // unique
  }
  __syncthreads();
  if (t == 0){
    int b_sel = 0;
    int c = *csel_sh;
    if (c >= 0){
      unsigned int cum = (c < 255) ? suf[c + 1] : 0u;
      for (int bi = 8 * c + 7; bi >= 8 * c; --bi){
        cum += lh[bi];
        if (cum >= (unsigned)ktop){ b_sel = bi; break; }
      }
    }
    *u_lo_sh = ((unsigned int)b_sel) << 21;
  }
  __syncthreads();
}

// FUSED score, 512 rows/block x 512 threads. Every block computes
// v = Wk^T(Wq [cur;ctx]) itself; Wk GEMV executed by threads 0-255 with the
// R16-exact code (bit-identical v). Mask bits first (latency under MLP);
// per wave 2 batches x 16 row-pairs, cand loads exec-masked on mask!=0.
__global__ __launch_bounds__(512) void k_score(const float* __restrict__ cur,
    const float* __restrict__ ctx, const float* __restrict__ Wq,
    const float* __restrict__ Wk, const float* __restrict__ cand,
    const int* __restrict__ mask, unsigned int* __restrict__ hist,
    unsigned int* __restrict__ scal_u, float* __restrict__ scores,
    float* __restrict__ out, int N){
  const float NLOG = logf(1e-10f);
  __shared__ float q[128];
  __shared__ float vpart[256];
  __shared__ float vsh[128];
  int t = threadIdx.x;
  int lane = t & 63, wave = t >> 6;               // 8 waves
  int hi = lane >> 5, hl = lane & 31;
  int rowbase0 = blockIdx.x * 512 + wave * 64;    // 64 rows per wave
  // ---- mask bits first (32 loads in flight; latency hides under MLP) ----
  unsigned int m_bits = 0u;
  #pragma unroll
  for (int ib = 0; ib < 2; ++ib){
    #pragma unroll
    for (int k = 0; k < 16; ++k){
      int r = rowbase0 + ib * 32 + 2 * k + hi;
      r = (r < N) ? r : (N - 1);
      if (mask[r]) m_bits |= (1u << (ib * 16 + k));
    }
  }
  // ---- housekeeping for k_tail (stream order: lands before tail launch) ----
  if (blockIdx.x >= 1 && blockIdx.x <= 4) hist[(blockIdx.x - 1) * 512 + t] = 0u;
  if (blockIdx.x == 5 && t < 16) scal_u[t] = 0u;
  // ---- redundant per-block MLP (Wq: 8 waves x 8 iters x 2 rows = 128) ----
  {
    float4 cb0 = ((const float4*)cur)[hl];
    float4 cb1 = ((const float4*)ctx)[hl];
    const float4* Wq4 = (const float4*)Wq;
    #pragma unroll 4
    for (int i = 0; i < 8; ++i){
      int row = wave * 16 + 2 * i + hi;
      float4 w0 = Wq4[row * 64 + hl];          // coalesced 512B per half-wave
      float4 w1 = Wq4[row * 64 + 32 + hl];
      float d = fmaf(w0.x, cb0.x, fmaf(w0.y, cb0.y, fmaf(w0.z, cb0.z, w0.w * cb0.w)));
      d = fmaf(w1.x, cb1.x, fmaf(w1.y, cb1.y, fmaf(w1.z, cb1.z, fmaf(w1.w, cb1.w, d))));
      d += __shfl_xor(d, 1, 64);
      d += __shfl_xor(d, 2, 64);
      d += __shfl_xor(d, 4, 64);
      d += __shfl_xor(d, 8, 64);
      d += __shfl_xor(d, 16, 64);
      if (hl == 0) q[row] = d;
    }
    __syncthreads();
    // Wk GEMV: threads 0-255 run R16's EXACT code -> bit-identical v
    if (t < 256){
      int col = t & 127, half = t >> 7;
      const float* wkp = Wk + half * 64 * 128 + col;
      const float* qp  = q + half * 64;
      float acc = 0.f;
      #pragma unroll 8
      for (int h = 0; h < 64; ++h) acc = fmaf(qp[h], wkp[h * 128], acc);
      vpart[t] = acc;
    }
    __syncthreads();
    if (t < 128) vsh[t] = vpart[t] + vpart[t + 128];
    __syncthreads();
  }
  float4 v4 = ((const float4*)vsh)[hl];
  const float4* cp = (const float4*)cand;
  // ---- 2 batches x 16 row-pairs (16 masked loads in flight per batch) ----
  #pragma unroll 1
  for (int ib = 0; ib < 2; ++ib){
    int rb = rowbase0 + ib * 32;
    float4 c[16];
    #pragma unroll
    for (int k = 0; k < 16; ++k){
      int r = rb + 2 * k + hi;
      r = (r < N) ? r : (N - 1);               // clamp keeps addr valid
      c[k] = make_float4(0.f, 0.f, 0.f, 0.f);
      if ((m_bits >> (ib * 16 + k)) & 1u) c[k] = cp[(size_t)r * 32 + hl];
    }
    float p[16];
    #pragma unroll
    for (int k = 0; k < 16; ++k)               // consume
      p[k] = fmaf(c[k].x, v4.x, fmaf(c[k].y, v4.y, fmaf(c[k].z, v4.z, c[k].w * v4.w)));
    #pragma unroll
    for (int k = 0; k < 16; ++k){              // 16 independent 5-shfl chains
      p[k] += __shfl_xor(p[k], 1, 64);
      p[k] += __shfl_xor(p[k], 2, 64);
      p[k] += __shfl_xor(p[k], 4, 64);
      p[k] += __shfl_xor(p[k], 8, 64);
      p[k] += __shfl_xor(p[k], 16, 64);
    }
    float sv = p[0];
    #pragma unroll
    for (int k = 1; k < 16; ++k) sv = (hl == k) ? p[k] : sv;
    if (hl < 16){                              // writer lanes
      int r = rb + 2 * hl + hi;
      if (r < N) scores[r] = ((m_bits >> (ib * 16 + hl)) & 1u) ? sv : NEG_INF;
    }
  }
  if (t < 128){                                // default output value, float4
    int o4 = blockIdx.x * 128 + t;
    if (o4 * 4 + 3 < N){
      ((float4*)out)[o4] = make_float4(NLOG, NLOG, NLOG, NLOG);
    } else {
      #pragma unroll
      for (int e = 0; e < 4; ++e){ int i = o4 * 4 + e; if (i < N) out[i] = NLOG; }
    }
  }
}

// Single tail launch, nb (<=49) blocks x 1024 thr, no polling, drop-free.
// (Byte-identical to R14's proven k_tail.)
__global__ __launch_bounds__(1024) void k_tail(const float* __restrict__ scores,
    unsigned int* __restrict__ scal_u, unsigned int* __restrict__ hist,
    float* __restrict__ zpart, unsigned int* __restrict__ cnt,
    unsigned int* __restrict__ buf_idx, float* __restrict__ buf_s,
    float* __restrict__ out, int N, int ktop, int nb){
  __shared__ unsigned int lh[2048];
  __shared__ unsigned int suf[256];
  __shared__ float s2[C2CAP];
  __shared__ unsigned int i2[C2CAP];
  __shared__ unsigned int cnt_l[MAXB], offs[MAXB];
  __shared__ float wred[16];
  __shared__ float rv[16], rl[16];
  __shared__ unsigned int ri[16];
  __shared__ float Z_sh, thr_sh, lnD_sh;
  __shared__ unsigned int u_lo_sh;
  __shared__ int csel_sh, pos_sh, C_sh, last_sh;
  int t = threadIdx.x, b = blockIdx.x;
  int lane = t & 63, wave = t >> 6;
  for (int k = t; k < 2048; k += 1024) lh[k] = 0u;
  if (t == 0){ pos_sh = 0; csel_sh = -1; }
  __syncthreads();
  // ---- phase 1: chunk -> REGISTERS, local hist, Z partial ----
  int base = b * 4096;
  int i0 = base + 4 * t;
  float4 s4 = make_float4(NEG_INF, NEG_INF, NEG_INF, NEG_INF);
  if (i0 + 3 < N) s4 = ((const float4*)scores)[(base >> 2) + t];
  else {
    if (i0     < N) s4.x = scores[i0];
    if (i0 + 1 < N) s4.y = scores[i0 + 1];
    if (i0 + 2 < N) s4.z = scores[i0 + 2];
  }
  float ez = 0.f;
#define HVISIT(s_) { float sx = (s_); if (sx > NEG_INF){ \
    atomicAdd(&lh[f2ord(sx) >> 21], 1u); ez += expf(sx); } }
  HVISIT(s4.x) HVISIT(s4.y) HVISIT(s4.z) HVISIT(s4.w)
#undef HVISIT
  #pragma unroll
  for (int off = 32; off; off >>= 1) ez += __shfl_xor(ez, off, 64);
  if (lane == 0) wred[wave] = ez;
  __syncthreads();                             // lh + wred complete
  // ---- phase 2: LOCAL suffix scan -> local top-ktop bin edge ----
  hist_select(lh, suf, &csel_sh, &u_lo_sh, ktop, t);
  // ---- phase 3: gather local superset (SLOT = chunk size: never drops),
  //      and flush LDS hist -> global hist (chains <= nb) ----
  unsigned int u_lo = u_lo_sh;
#define GVISIT(s_, i_) { float sx = (s_); \
    if (sx > NEG_INF && f2ord(sx) >= u_lo && (i_) < N){ \
      int p = atomicAdd(&pos_sh, 1); \
      buf_s[(size_t)b * SLOT + p] = sx; \
      buf_idx[(size_t)b * SLOT + p] = (unsigned int)(i_); } }
  GVISIT(s4.x, i0) GVISIT(s4.y, i0 + 1) GVISIT(s4.z, i0 + 2) GVISIT(s4.w, i0 + 3)
#undef GVISIT
  for (int k = t; k < 2048; k += 1024){
    unsigned int cc = lh[k];
    if (cc) atomicAdd(&hist[k], cc);
  }
  __syncthreads();                             // drains buf stores + hist atomics
  if (t == 0){
    cnt[b] = (unsigned int)pos_sh;
    float z = 0.f;
    for (int w = 0; w < 16; ++w) z += wred[w];
    zpart[b] = z;
    __threadfence();
    unsigned int old = atomicAdd(&scal_u[8], 1u);   // single-shot, chain <= nb
    last_sh = (old == (unsigned)(nb - 1));
  }
  __syncthreads();
  if (!last_sh) return;
  __threadfence();
  // ---- fin (last block only): all global reads independent + pipelined ----
  if (t < nb) cnt_l[t] = cnt[t];
  for (int k = t; k < 2048; k += 1024) lh[k] = hist[k];   // coalesced, 2 iters
  {
    float z = 0.f;
    if (t < 64){
      z = (t < nb) ? zpart[t] : 0.f;
      #pragma unroll
      for (int off = 32; off; off >>= 1) z += __shfl_xor(z, off, 64);
    }
    if (t == 0){ Z_sh = z; thr_sh = NEG_INF; pos_sh = 0; csel_sh = -1; }
  }
  __syncthreads();
  if (t == 0){
    unsigned int acc = 0;
    for (int b2 = 0; b2 < nb; ++b2){ offs[b2] = acc; acc += cnt_l[b2]; }
    C_sh = (int)acc;
  }
  __syncthreads();
  // global v50 bin edge from the FULL global hist (R7 semantics)
  hist_select(lh, suf, &csel_sh, &u_lo_sh, ktop, t);
  unsigned int u_lo2 = u_lo_sh;
  int C = C_sh;
  // indexed compact sweep: p -> (block, j) via LDS binary search; all loads
  // independent across p-iterations (C ~ 3.2k -> ~4 strided iterations)
  for (int p = t; p < C; p += 1024){
    int lo = 0, hi2 = nb - 1;
    while (lo < hi2){
      int mid = (lo + hi2 + 1) >> 1;
      if (offs[mid] <= (unsigned)p) lo = mid; else hi2 = mid - 1;
    }
    unsigned int j = (unsigned)p - offs[lo];
    float sx = buf_s[(size_t)lo * SLOT + j];
    if (sx > NEG_INF && f2ord(sx) >= u_lo2){
      int q = atomicAdd(&pos_sh, 1);
      if (q < C2CAP){ s2[q] = sx; i2[q] = buf_idx[(size_t)lo * SLOT + j]; }
    }
  }
  __syncthreads();
  int C2 = (pos_sh > C2CAP) ? C2CAP : pos_sh;
  // ---- exact rank-select on C2 entries (broadcast LDS reads) ----
  if (C2 > ktop){
    for (int j = t; j < C2; j += 1024){
      float sj = s2[j];
      int g = 0, e = 0;
      for (int k2 = 0; k2 < C2; ++k2){
        float sk = s2[k2];
        g += (sk > sj);
        e += (sk == sj);
      }
      if (g < ktop && g + e >= ktop) thr_sh = sj;   // all writers same value
    }
  }
  __syncthreads();
  float s_thr = thr_sh;
  float part = 0.f;
  for (int j = t; j < C2; j += 1024){
    float sj = s2[j];
    if (sj >= s_thr) part += expf(sj);
  }
  #pragma unroll
  for (int off = 32; off; off >>= 1) part += __shfl_xor(part, off, 64);
  if (lane == 0) wred[wave] = part;
  __syncthreads();
  if (t == 0){
    float T = 0.f;
    for (int w = 0; w < 16; ++w) T += wred[w];
    lnD_sh = logf(T + 1e-10f * Z_sh);          // D = Z*(sum_top p + 1e-10)
  }
  __syncthreads();
  float lnD = lnD_sh;
  for (int j = t; j < C2; j += 1024){          // rewrite included entries
    float sj = s2[j];
    if (sj >= s_thr) out[i2[j]] = logf(expf(sj - lnD) + 1e-10f);
  }
  float bestv = NEG_INF, bestlogit = NEG_INF;  // gumbel categorical
  unsigned int bestidx = 0xFFFFFFFFu;
  for (int j = t; j < C2; j += 1024){
    float sj = s2[j];
    if (sj >= s_thr){
      unsigned int idx = i2[j];
      float logit = sj - lnD;                  // log(filtered)
      float val = logit + gumbel_from_idx(idx);
      if (val > bestv || (val == bestv && idx < bestidx)){
        bestv = val; bestlogit = logit; bestidx = idx;
      }
    }
  }
  #pragma unroll
  for (int off = 32; off; off >>= 1){
    float ov = __shfl_xor(bestv, off, 64);
    float ol = __shfl_xor(bestlogit, off, 64);
    unsigned int oi = (unsigned int)__shfl_xor((int)bestidx, off, 64);
    if (ov > bestv || (ov == bestv && oi < bestidx)){
      bestv = ov; bestlogit = ol; bestidx = oi;
    }
  }
  if (lane == 0){ rv[wave] = bestv; rl[wave] = bestlogit; ri[wave] = bestidx; }
  __syncthreads();
  if (t == 0){
    for (int w = 1; w < 16; ++w){
      if (rv[w] > rv[0] || (rv[w] == rv[0] && ri[w] < ri[0])){
        rv[0] = rv[w]; rl[0] = rl[w]; ri[0] = ri[w];
      }
    }
    out[N] = rl[0];                 // log_prob_action
    out[N + 1] = (float)ri[0];      // action_idx
  }
}

extern "C" void kernel_launch(void* const* d_in, const int* in_sizes, int n_in,
                              void* d_out, int out_size, void* d_ws, size_t ws_size,
                              hipStream_t stream){
  const float* cur  = (const float*)d_in[0];
  const float* ctx  = (const float*)d_in[1];
  const float* cand = (const float*)d_in[2];
  const float* Wq   = (const float*)d_in[3];
  const float* Wk   = (const float*)d_in[4];
  const int*   mask = (const int*)d_in[5];
  int N = in_sizes[5];
  float* out = (float*)d_out;

  char* ws = (char*)d_ws;
  unsigned int* scal_u  = (unsigned int*)ws;                  // 64B ([8]=done)
  float*        zpart   = (float*)(ws + 1024);                // MAXB*4
  unsigned int* cnt     = (unsigned int*)(ws + 1536);         // MAXB*4
  unsigned int* hist    = (unsigned int*)(ws + 4096);         // 8KB
  float*        scores  = (float*)(ws + 16384);               // N*4, 16B-aligned
  char*         bufbase = ws + 16384 + (((size_t)N * 4 + 255) & ~255ull);
  float*        buf_s   = (float*)bufbase;                    // MAXB*SLOT*4 = 1MB
  unsigned int* buf_idx = (unsigned int*)(bufbase + (size_t)MAXB * SLOT * 4);

  int ktop = N / 2; if (ktop < 1) ktop = 1; if (ktop > 50) ktop = 50;
  int g_score = (N + 511) / 512;        // 512 rows per block -> 391 blocks
  int nb = (N + 4095) / 4096;           // 49 for N=200000
  if (nb > MAXB) nb = MAXB;             // (N fixed at 200000; guard only)

  k_score<<<g_score, 512, 0, stream>>>(cur, ctx, Wq, Wk, cand, mask,
                                       hist, scal_u, scores, out, N);
  k_tail<<<nb, 1024, 0, stream>>>(scores, scal_u, hist, zpart, cnt,
                                  buf_idx, buf_s, out, N, ktop, nb);
}